// Round 6
// baseline (254.390 us; speedup 1.0000x reference)
//
#include <hip/hip_runtime.h>

#define EMBED 1024
#define HEADS 16
#define HDIM  64

typedef __attribute__((ext_vector_type(8))) short bf16x8;
typedef __attribute__((ext_vector_type(8))) _Float16 f16x8;
typedef __attribute__((ext_vector_type(4))) float f32x4;

#define AS1 __attribute__((address_space(1)))
#define AS3 __attribute__((address_space(3)))

#if __has_builtin(__builtin_amdgcn_exp2f)
#define EXP2F(x) __builtin_amdgcn_exp2f(x)
#else
#define EXP2F(x) exp2f(x)
#endif

__device__ __forceinline__ unsigned bf16_rne(float f) {
    unsigned u = __float_as_uint(f);
    return (u + 0x7FFFu + ((u >> 16) & 1u)) >> 16;
}

// ---------------------------------------------------------------------------
// Kernel 0: fused cast fp32 -> fp16 (RNE) for X (scale 1) and Wq/Wk/Wv
// (scale 256, undone in GEMM epilogue).  One launch instead of four.
// ---------------------------------------------------------------------------
__global__ __launch_bounds__(256)
void cast_all(const float* __restrict__ X,  const float* __restrict__ Wq,
              const float* __restrict__ Wk, const float* __restrict__ Wv,
              short* __restrict__ Xh, short* __restrict__ Wh)
{
    const int bid = blockIdx.x;
    const float* in;
    short* out;
    float scale;
    int base;
    if (bid < 4096) { in = X; out = Xh; scale = 1.0f; base = bid; }
    else {
        const int wsel = (bid - 4096) >> 9;        // 0..2
        in  = (wsel == 0) ? Wq : (wsel == 1) ? Wk : Wv;
        out = Wh + wsel * 1048576;
        scale = 256.0f;
        base = (bid - 4096) & 511;
    }
    const int i = (base * 256 + threadIdx.x) * 8;
    float4 a = *(const float4*)(in + i);
    float4 b = *(const float4*)(in + i + 4);
    float f[8] = {a.x, a.y, a.z, a.w, b.x, b.y, b.z, b.w};
    union { _Float16 h[8]; uint4 v; } H;
#pragma unroll
    for (int e = 0; e < 8; ++e) H.h[e] = (_Float16)(f[e] * scale);
    *(uint4*)(out + i) = H.v;
}

// ---------------------------------------------------------------------------
// Kernel 1: QKV projection, 256x128 tile / BK=64 / 8-wave / 8-phase,
// TRIPLE-buffered K-tiles with continuous staging and EXACT vmcnt(2) chain:
//   - grid 768 = 8 XCD x 3 bx x 32 by -> 1 block/CU, 3 exact rounds (no tail);
//     same-bx blocks clustered per XCD -> B panel L2-resident.
//   - LDS 144 KiB: 3 bufs x (A 256x64 | B 128x64) fp16, XOR-swizzled via
//     pre-swizzled global source + same XOR on ds_read (rule 21).
//   - iter i (K-tiles 2i -> bufE, 2i+1 -> bufO):
//       p0..p2 stage kt 2i+2 -> bufS1   (read NEXT iter p0-3: 4+ phase lead)
//       p4..p6 stage kt 2i+3 -> bufE    (read NEXT iter p4-7: 4+ phase lead;
//                                        WAR-safe: bufE reads end at p3)
//     every phase: {8 ds_read_b128; stage; vmcnt(2); barrier; 8 MFMA; barrier}
//     Retirement induction: stage at phase s retired by wait at s+2
//     (continuous 2-loads-per-stage-phase issue), so every buffer is fully
//     landed >=1 phase before its first read, in ALL waves (wait precedes
//     barrier in each wave).  vmcnt never drains to 0 until the last iter.
// ---------------------------------------------------------------------------
#define STAGE_A(buf, h, kt) do {                                              \
    const short* s0_ = baseA + ((h) * 128) * EMBED + (kt) * 64;               \
    short* d_ = &sh[(buf) * 24576 + (h) * 8192 + t * 8];                      \
    __builtin_amdgcn_global_load_lds((const AS1 void*)s0_, (AS3 void*)d_, 16, 0, 0); \
    __builtin_amdgcn_global_load_lds((const AS1 void*)(s0_ + 64 * EMBED), (AS3 void*)(d_ + 4096), 16, 0, 0); \
} while (0)

#define STAGE_B(buf, kt) do {                                                 \
    const short* s0_ = baseB + (kt) * 64;                                     \
    short* d_ = &sh[(buf) * 24576 + 16384 + t * 8];                           \
    __builtin_amdgcn_global_load_lds((const AS1 void*)s0_, (AS3 void*)d_, 16, 0, 0); \
    __builtin_amdgcn_global_load_lds((const AS1 void*)(s0_ + 64 * EMBED), (AS3 void*)(d_ + 4096), 16, 0, 0); \
} while (0)

__global__ __launch_bounds__(512, 2)
void qkv_mfma(const short* __restrict__ Xh, const short* __restrict__ Wh,
              const float* __restrict__ bq, const float* __restrict__ bk,
              const float* __restrict__ bv,
              short* __restrict__ Qb, short* __restrict__ Kb, short* __restrict__ Vn)
{
    __shared__ short sh[73728];   // 144 KiB: 3 x (A 16384 | B 8192) shorts

    const int t = threadIdx.x;
    const int lane = t & 63, quad = lane >> 4, l16 = lane & 15;
    const int w = t >> 6, wm = w >> 1, wn = w & 1;   // 4M x 2N waves, 64x64 each

    // XCD-swizzled 1-D grid: id&7 = XCD; per XCD 3 bx (B panels) x 32 by.
    const int id  = blockIdx.x;                 // 0..767
    const int xcd = id & 7, loc = id >> 3;      // loc 0..95
    const int bx  = xcd * 3 + (loc >> 5);       // 0..23
    const int by  = loc & 31;                   // 0..31
    const int n0 = bx * 128, m0 = by * 256;

    const int r  = t >> 3;                       // 0..63
    const int k8 = ((t & 7) ^ (r & 7)) * 8;      // swizzled k element offset
    const short* baseA = Xh + (size_t)(m0 + r) * EMBED + k8;
    const short* baseB = Wh + (size_t)(n0 + r) * EMBED + k8;

    const int xk0 = ((quad * 16)      ^ ((l16 & 7) << 4)) >> 1;  // ks=0
    const int xk1 = ((64 + quad * 16) ^ ((l16 & 7) << 4)) >> 1;  // ks=1
    const int aBase = (wm >> 1) * 8192 + ((wm & 1) * 64 + l16) * 64;  // + mi*1024
    const int bBase = 16384 + (wn * 64 + l16) * 64;                    // + ni*1024

    f32x4 acc[4][4];
#pragma unroll
    for (int i = 0; i < 4; ++i)
#pragma unroll
        for (int j = 0; j < 4; ++j) acc[i][j] = (f32x4){0.f, 0.f, 0.f, 0.f};

    // ---- prologue: kt0 -> buf0, kt1 -> buf1 (12 loads), full drain once
    STAGE_A(0, 0, 0); STAGE_A(0, 1, 0); STAGE_B(0, 0);
    STAGE_A(1, 0, 1); STAGE_A(1, 1, 1); STAGE_B(1, 1);
    asm volatile("s_waitcnt vmcnt(0)" ::: "memory");
    __builtin_amdgcn_s_barrier();

    int bufE = 0;
#pragma unroll 1
    for (int i = 0; i < 8; ++i) {
        const int bufO  = (bufE + 1 == 3) ? 0 : bufE + 1;
        const int bufS1 = (bufO + 1 == 3) ? 0 : bufO + 1;  // kt 2i+2 target
        const int ktc = 2 * i + 2, ktd = 2 * i + 3;        // ktd -> bufE
        const bool more = (i < 7);
        const int obE = bufE * 24576, obO = bufO * 24576;
#pragma unroll
        for (int p = 0; p < 8; ++p) {
            const int q = p & 3;
            const int ob = (p < 4) ? obE : obO;
            const int miH = (q & 1) * 2, niH = (q >> 1) * 2;

            // 1) ds_read this phase's 2x2 quadrant fragments (8 x b128)
            f16x8 af[2][2], bf[2][2];
#pragma unroll
            for (int mi = 0; mi < 2; ++mi) {
                const int o = ob + aBase + (miH + mi) * 1024;
                af[mi][0] = *(const f16x8*)&sh[o + xk0];
                af[mi][1] = *(const f16x8*)&sh[o + xk1];
            }
#pragma unroll
            for (int ni = 0; ni < 2; ++ni) {
                const int o = ob + bBase + (niH + ni) * 1024;
                bf[ni][0] = *(const f16x8*)&sh[o + xk0];
                bf[ni][1] = *(const f16x8*)&sh[o + xk1];
            }

            // 2) stage one half-tile (2 loads) per schedule
            if (more) {
                if      (p == 0) STAGE_A(bufS1, 0, ktc);
                else if (p == 1) STAGE_A(bufS1, 1, ktc);
                else if (p == 2) STAGE_B(bufS1, ktc);
                else if (p == 4) STAGE_A(bufE, 0, ktd);
                else if (p == 5) STAGE_A(bufE, 1, ktd);
                else if (p == 6) STAGE_B(bufE, ktd);
            }

            // 3) exact counted wait + barrier
            if (more) asm volatile("s_waitcnt vmcnt(2)" ::: "memory");
            else      asm volatile("s_waitcnt vmcnt(0)" ::: "memory");
            __builtin_amdgcn_s_barrier();

            // 4) 8 MFMA under raised priority
            __builtin_amdgcn_s_setprio(1);
#pragma unroll
            for (int mi = 0; mi < 2; ++mi)
#pragma unroll
                for (int ni = 0; ni < 2; ++ni) {
                    acc[miH + mi][niH + ni] = __builtin_amdgcn_mfma_f32_16x16x32_f16(
                        af[mi][0], bf[ni][0], acc[miH + mi][niH + ni], 0, 0, 0);
                    acc[miH + mi][niH + ni] = __builtin_amdgcn_mfma_f32_16x16x32_f16(
                        af[mi][1], bf[ni][1], acc[miH + mi][niH + ni], 0, 0, 0);
                }
            __builtin_amdgcn_s_setprio(0);
            __builtin_amdgcn_s_barrier();
        }
        bufE = bufS1;
    }

    // ---- epilogue: bias+scale -> bf16, 64x128 slab reorg, 32B stores
    const int mat = n0 >> 10;                 // 0=q 1=k 2=v (128 | 1024)
    const float* bias = (mat == 0) ? bq : (mat == 1) ? bk : bv;
    short* Out = (mat == 0) ? Qb : (mat == 1) ? Kb : Vn;
    const float s = (mat == 0) ? 0.125f * 1.4426950408889634f : 1.0f;
    const float fs = s * (1.0f / 256.0f);
    const int nm0 = n0 & 1023;
    float bias_v[4];
#pragma unroll
    for (int ni = 0; ni < 4; ++ni) bias_v[ni] = bias[nm0 + wn * 64 + ni * 16 + l16] * s;
    const int bidx = m0 >> 10;
    const int l0   = m0 & 1023;

    // Slab: [64 rows][132 shorts]
#pragma unroll
    for (int mi = 0; mi < 4; ++mi) {
        __syncthreads();
#pragma unroll
        for (int ni = 0; ni < 4; ++ni) {
            const int col = wn * 64 + ni * 16 + l16;
#pragma unroll
            for (int rr = 0; rr < 4; ++rr) {
                const int srow = wm * 16 + quad * 4 + rr;   // 0..63
                sh[srow * 132 + col] =
                    (short)(unsigned short)bf16_rne(fmaf(acc[mi][ni][rr], fs, bias_v[ni]));
            }
        }
        __syncthreads();
        const int srowR = t >> 3;            // 0..63
        const int cblk  = (t & 7) * 16;      // 0..112
        uint4 v0 = *(uint4*)&sh[srowR * 132 + cblk];
        uint4 v1 = *(uint4*)&sh[srowR * 132 + cblk + 8];
        const int wmS = srowR >> 4, rloc = srowR & 15;
        const int l = l0 + wmS * 64 + mi * 16 + rloc;
        const int nm = nm0 + cblk;
        const int head = nm >> 6, d0 = nm & 63;
        short* pDst = Out + ((size_t)(bidx * HEADS + head) * 1024 + l) * 64 + d0;
        *(uint4*)pDst = v0;
        *(uint4*)(pDst + 8) = v1;
    }
}

// ---------------------------------------------------------------------------
// Kernel 1b: V transpose  [bh][l][d] -> [bh][d][l]  (bf16, conflict-free).
// ---------------------------------------------------------------------------
__global__ __launch_bounds__(256)
void vtrans(const short* __restrict__ Vn, short* __restrict__ Vt)
{
    __shared__ int tile[64 * 65];
    const int t  = threadIdx.x;
    const int lt = blockIdx.x;   // 0..15
    const int bh = blockIdx.y;   // 0..127
    const int lq = t >> 3, dc = (t & 7) * 8;
    const short* src = Vn + ((size_t)bh * 1024 + lt * 64) * 64;
#pragma unroll
    for (int h = 0; h < 2; ++h) {
        const int l = lq + h * 32;
        union { uint4 v; unsigned short us[8]; } ld;
        ld.v = *(const uint4*)&src[l * 64 + dc];
#pragma unroll
        for (int j = 0; j < 8; ++j) tile[(dc + j) * 65 + l] = ld.us[j];
    }
    __syncthreads();
    const int dr = t >> 3, lblk = (t & 7) * 8;
    short* dst = Vt + (size_t)bh * 64 * 1024 + lt * 64;
#pragma unroll
    for (int h = 0; h < 2; ++h) {
        const int d = dr + h * 32;
        union { uint4 v; unsigned short us[8]; } o;
#pragma unroll
        for (int j = 0; j < 8; ++j) o.us[j] = (unsigned short)tile[d * 65 + lblk + j];
        *(uint4*)&dst[(size_t)d * 1024 + lblk] = o.v;
    }
}

// ---------------------------------------------------------------------------
// Kernel 2: MFMA flash attention, S^T form, ZERO-SHUFFLE P.
//   Proven round-2 schedule (prefetch at top, one __syncthreads per kt).
//   XCD-aware 1-D grid swizzle: all 16 qt-blocks of one (h,b) on ONE XCD.
//   K staged with rows bit-permuted (prow) so QK^T C-rows land exactly in
//   PV's B-fragment key slots.  Fixed softmax reference m=0 (exp2 domain).
// ---------------------------------------------------------------------------
__global__ __launch_bounds__(256)
void attn_mfma(const short* __restrict__ Qb, const short* __restrict__ Kb,
               const short* __restrict__ Vt, float* __restrict__ out)
{
    __shared__ short smem[20480];   // Qs 4096 | Ks0 | Ks1 | Vs0 | Vs1 (4096 each)

    const int t  = threadIdx.x;
    const int id  = blockIdx.x;                  // 0..2047
    const int xcd = id & 7;
    const int loc = id >> 3;                     // 0..255
    const int bh  = xcd * 16 + (loc >> 4);       // 0..127
    const int qt  = loc & 15;
    const int lane = t & 63, quad = lane >> 4, l16 = lane & 15;
    const int w = t >> 6;
    const int srow = t & 63, schunk = t >> 6;

    // prow = [b4 | b3 b2 | b5 | b1 b0] of srow -> C-layout rows == PV B-slots
    const int prow = ((srow >> 4) & 1) * 32 + ((srow >> 2) & 3) * 8
                   + (srow >> 5) * 4 + (srow & 3);

    {
        const short* gq = Qb + ((size_t)bh * 1024 + qt * 64 + srow) * 64 + schunk * 8;
        __builtin_amdgcn_global_load_lds((const AS1 void*)gq,        (AS3 void*)&smem[t * 8],         16, 0, 0);
        __builtin_amdgcn_global_load_lds((const AS1 void*)(gq + 32), (AS3 void*)&smem[(t + 256) * 8], 16, 0, 0);
        const short* gk = Kb + ((size_t)bh * 1024 + prow) * 64 + schunk * 8;
        __builtin_amdgcn_global_load_lds((const AS1 void*)gk,        (AS3 void*)&smem[4096 + t * 8],         16, 0, 0);
        __builtin_amdgcn_global_load_lds((const AS1 void*)(gk + 32), (AS3 void*)&smem[4096 + (t + 256) * 8], 16, 0, 0);
        const short* gv = Vt + ((size_t)bh * 64 + srow) * 1024 + schunk * 8;
        __builtin_amdgcn_global_load_lds((const AS1 void*)gv,        (AS3 void*)&smem[12288 + t * 8],         16, 0, 0);
        __builtin_amdgcn_global_load_lds((const AS1 void*)(gv + 32), (AS3 void*)&smem[12288 + (t + 256) * 8], 16, 0, 0);
    }
    __syncthreads();

    bf16x8 qfrag[2];
#pragma unroll
    for (int kh = 0; kh < 2; ++kh)
        qfrag[kh] = *(const bf16x8*)&smem[((quad + 4 * kh) * 64 + w * 16 + l16) * 8];

    f32x4 O[4];
#pragma unroll
    for (int i = 0; i < 4; ++i) O[i] = (f32x4){0.f, 0.f, 0.f, 0.f};
    float l_i = 0.f;

    for (int kt = 0; kt < 16; ++kt) {
        const int cur = kt & 1, nxt = cur ^ 1;
        if (kt < 15) {
            const short* gk = Kb + ((size_t)bh * 1024 + (kt + 1) * 64 + prow) * 64 + schunk * 8;
            __builtin_amdgcn_global_load_lds((const AS1 void*)gk,        (AS3 void*)&smem[4096 + nxt * 4096 + t * 8],         16, 0, 0);
            __builtin_amdgcn_global_load_lds((const AS1 void*)(gk + 32), (AS3 void*)&smem[4096 + nxt * 4096 + (t + 256) * 8], 16, 0, 0);
            const short* gv = Vt + ((size_t)bh * 64 + srow) * 1024 + (kt + 1) * 64 + schunk * 8;
            __builtin_amdgcn_global_load_lds((const AS1 void*)gv,        (AS3 void*)&smem[12288 + nxt * 4096 + t * 8],         16, 0, 0);
            __builtin_amdgcn_global_load_lds((const AS1 void*)(gv + 32), (AS3 void*)&smem[12288 + nxt * 4096 + (t + 256) * 8], 16, 0, 0);
        }

        const short* Kc = &smem[4096 + cur * 4096];
        const short* Vc = &smem[12288 + cur * 4096];

        f32x4 ST[4];
#pragma unroll
        for (int mi = 0; mi < 4; ++mi) ST[mi] = (f32x4){0.f, 0.f, 0.f, 0.f};
        __builtin_amdgcn_s_setprio(1);
#pragma unroll
        for (int kh = 0; kh < 2; ++kh)
#pragma unroll
            for (int mi = 0; mi < 4; ++mi) {
                const bf16x8 ka = *(const bf16x8*)&Kc[((quad + 4 * kh) * 64 + mi * 16 + l16) * 8];
                ST[mi] = __builtin_amdgcn_mfma_f32_16x16x32_bf16(ka, qfrag[kh], ST[mi], 0, 0, 0);
            }
        __builtin_amdgcn_s_setprio(0);

        // softmax numerator, fixed reference m=0 (exp2 domain, |s| ~ O(4))
        float p[4][4];
        float rs = 0.f;
#pragma unroll
        for (int mi = 0; mi < 4; ++mi)
#pragma unroll
            for (int rr = 0; rr < 4; ++rr) { p[mi][rr] = EXP2F(ST[mi][rr]); rs += p[mi][rr]; }
        l_i += rs;

        // zero-shuffle pack: lane already holds its PV B-fragment keys.
        union { unsigned u[4]; bf16x8 v; } pa[2];
#pragma unroll
        for (int kh = 0; kh < 2; ++kh) {
            asm("v_cvt_pk_bf16_f32 %0, %1, %2" : "=v"(pa[kh].u[0]) : "v"(p[kh][0]),     "v"(p[kh][1]));
            asm("v_cvt_pk_bf16_f32 %0, %1, %2" : "=v"(pa[kh].u[1]) : "v"(p[kh][2]),     "v"(p[kh][3]));
            asm("v_cvt_pk_bf16_f32 %0, %1, %2" : "=v"(pa[kh].u[2]) : "v"(p[kh + 2][0]), "v"(p[kh + 2][1]));
            asm("v_cvt_pk_bf16_f32 %0, %1, %2" : "=v"(pa[kh].u[3]) : "v"(p[kh + 2][2]), "v"(p[kh + 2][3]));
        }

        __builtin_amdgcn_s_setprio(1);
#pragma unroll
        for (int kh = 0; kh < 2; ++kh)
#pragma unroll
            for (int mi = 0; mi < 4; ++mi) {
                const bf16x8 va = *(const bf16x8*)&Vc[((quad + 4 * kh) * 64 + mi * 16 + l16) * 8];
                O[mi] = __builtin_amdgcn_mfma_f32_16x16x32_bf16(va, pa[kh].v, O[mi], 0, 0, 0);
            }
        __builtin_amdgcn_s_setprio(0);

        __syncthreads();
    }

    // l_i currently sums this lane's 16 keys x16 kt; complete over the key dim
    l_i += __shfl_xor(l_i, 16);
    l_i += __shfl_xor(l_i, 32);

    float* Os = (float*)&smem[4096];
    const float inv = 1.0f / l_i;
#pragma unroll
    for (int mi = 0; mi < 4; ++mi) {
        f32x4 v;
#pragma unroll
        for (int rr = 0; rr < 4; ++rr) v[rr] = O[mi][rr] * inv;
        *(f32x4*)&Os[(w * 16 + l16) * 68 + mi * 16 + quad * 4] = v;
    }
    __syncthreads();
    {
        const int q = t >> 2, dbase = (t & 3) * 16;
        float* op = out + ((size_t)bh * 1024 + qt * 64 + q) * 64 + dbase;
#pragma unroll
        for (int i = 0; i < 4; ++i)
            *(float4*)&op[i * 4] = *(float4*)&Os[q * 68 + dbase + i * 4];
    }
}

extern "C" void kernel_launch(void* const* d_in, const int* in_sizes, int n_in,
                              void* d_out, int out_size, void* d_ws, size_t ws_size,
                              hipStream_t stream)
{
    const float* X  = (const float*)d_in[0];
    const float* Wq = (const float*)d_in[1];
    const float* bq = (const float*)d_in[2];
    const float* Wk = (const float*)d_in[3];
    const float* bk = (const float*)d_in[4];
    const float* Wv = (const float*)d_in[5];
    const float* bv = (const float*)d_in[6];
    float* out = (float*)d_out;

    const size_t per = (size_t)8 * HEADS * 1024 * HDIM;   // 8,388,608
    short* Qb = (short*)d_ws;
    short* Kb = Qb + per;
    short* Vt = Kb + per;
    short* Xh = Vt + per;                 // fp16
    short* Wh = Xh + per;                 // fp16 (x256), 3 x 1,048,576
    short* Vn = (short*)d_out;            // scratch: V natural layout (overwritten by attn)

    cast_all<<<4096 + 3 * 512, 256, 0, stream>>>(X, Wq, Wk, Wv, Xh, Wh);

    qkv_mfma<<<768, 512, 0, stream>>>(Xh, Wh, bq, bk, bv, Qb, Kb, Vn);
    vtrans<<<dim3(16, 128), 256, 0, stream>>>(Vn, Vt);
    attn_mfma<<<2048, 256, 0, stream>>>(Qb, Kb, Vt, out);
}

// Round 7
// 228.885 us; speedup vs baseline: 1.1114x; 1.1114x over previous
//
#include <hip/hip_runtime.h>

#define EMBED 1024
#define HEADS 16
#define HDIM  64

typedef __attribute__((ext_vector_type(8))) short bf16x8;
typedef __attribute__((ext_vector_type(8))) _Float16 f16x8;
typedef __attribute__((ext_vector_type(4))) float f32x4;

#define AS1 __attribute__((address_space(1)))
#define AS3 __attribute__((address_space(3)))

#if __has_builtin(__builtin_amdgcn_exp2f)
#define EXP2F(x) __builtin_amdgcn_exp2f(x)
#else
#define EXP2F(x) exp2f(x)
#endif

__device__ __forceinline__ unsigned bf16_rne(float f) {
    unsigned u = __float_as_uint(f);
    return (u + 0x7FFFu + ((u >> 16) & 1u)) >> 16;
}

// ---------------------------------------------------------------------------
// Kernel 0: fused cast fp32 -> fp16 (RNE) for X (scale 1) and Wq/Wk/Wv
// (scale 256, undone in GEMM epilogue).
// ---------------------------------------------------------------------------
__global__ __launch_bounds__(256)
void cast_all(const float* __restrict__ X,  const float* __restrict__ Wq,
              const float* __restrict__ Wk, const float* __restrict__ Wv,
              short* __restrict__ Xh, short* __restrict__ Wh)
{
    const int bid = blockIdx.x;
    const float* in;
    short* out;
    float scale;
    int base;
    if (bid < 4096) { in = X; out = Xh; scale = 1.0f; base = bid; }
    else {
        const int wsel = (bid - 4096) >> 9;        // 0..2
        in  = (wsel == 0) ? Wq : (wsel == 1) ? Wk : Wv;
        out = Wh + wsel * 1048576;
        scale = 256.0f;
        base = (bid - 4096) & 511;
    }
    const int i = (base * 256 + threadIdx.x) * 8;
    float4 a = *(const float4*)(in + i);
    float4 b = *(const float4*)(in + i + 4);
    float f[8] = {a.x, a.y, a.z, a.w, b.x, b.y, b.z, b.w};
    union { _Float16 h[8]; uint4 v; } H;
#pragma unroll
    for (int e = 0; e < 8; ++e) H.h[e] = (_Float16)(f[e] * scale);
    *(uint4*)(out + i) = H.v;
}

// ---------------------------------------------------------------------------
// Kernel 1: QKV projection -- ROUND-4 PROVEN VERSION (256x256 tile, BK=64,
// 8-wave 8-phase, dim3(12,32) grid: bx fastest -> 12 blocks sharing one A
// panel co-scheduled, A served from L2/L3).  Measured 80.1 us / FETCH 79MB.
// ---------------------------------------------------------------------------
#define STAGE_A(buf, h, kt) do {                                              \
    const short* s0_ = baseA + ((h) * 128) * EMBED + (kt) * 64;               \
    short* d_ = &sh[(buf) * 32768 + (h) * 8192 + t * 8];                      \
    __builtin_amdgcn_global_load_lds((const AS1 void*)s0_, (AS3 void*)d_, 16, 0, 0); \
    __builtin_amdgcn_global_load_lds((const AS1 void*)(s0_ + 64 * EMBED), (AS3 void*)(d_ + 4096), 16, 0, 0); \
} while (0)

#define STAGE_B(buf, h, kt) do {                                              \
    const short* s0_ = baseB + ((h) * 32) * EMBED + (kt) * 64;                \
    short* d_ = &sh[(buf) * 32768 + 16384 + (h) * 8192 + t * 8];              \
    __builtin_amdgcn_global_load_lds((const AS1 void*)s0_, (AS3 void*)d_, 16, 0, 0); \
    __builtin_amdgcn_global_load_lds((const AS1 void*)(s0_ + 128 * EMBED), (AS3 void*)(d_ + 4096), 16, 0, 0); \
} while (0)

__global__ __launch_bounds__(512, 2)
void qkv_mfma(const short* __restrict__ Xh, const short* __restrict__ Wh,
              const float* __restrict__ bq, const float* __restrict__ bk,
              const float* __restrict__ bv,
              short* __restrict__ Qb, short* __restrict__ Kb, short* __restrict__ Vn)
{
    __shared__ short sh[65536];   // 128 KiB

    const int t = threadIdx.x;
    const int lane = t & 63, quad = lane >> 4, l16 = lane & 15;
    const int w = t >> 6, wm = w >> 2, wn = w & 3;

    const int n0 = blockIdx.x * 256;   // 0..11 -> Q/K/V column panel
    const int m0 = blockIdx.y * 256;   // 0..31

    const int r  = t >> 3;                       // 0..63
    const int k8 = ((t & 7) ^ (r & 7)) * 8;      // swizzled k element offset
    const short* baseA = Xh + (size_t)(m0 + r) * EMBED + k8;
    const short* baseB = Wh + (size_t)(n0 + (r & 31) + (r >> 5) * 64) * EMBED + k8;

    const int xk0 = ((quad * 16)      ^ ((l16 & 7) << 4)) >> 1;  // ks=0
    const int xk1 = ((64 + quad * 16) ^ ((l16 & 7) << 4)) >> 1;  // ks=1
    const int aOff = wm * 8192 + l16 * 64;                 // + mi*1024
    const int bOff = 16384 + wn * 2048 + l16 * 64;

    f32x4 acc[8][4];
#pragma unroll
    for (int i = 0; i < 8; ++i)
#pragma unroll
        for (int j = 0; j < 4; ++j) acc[i][j] = (f32x4){0.f, 0.f, 0.f, 0.f};

    STAGE_B(0, 0, 0);
    STAGE_A(0, 0, 0);
    STAGE_A(0, 1, 0);
    STAGE_B(0, 1, 0);
    asm volatile("s_waitcnt vmcnt(4)" ::: "memory");
    __builtin_amdgcn_s_barrier();

#pragma unroll 1
    for (int i = 0; i < 8; ++i) {
        const int ktb = 2 * i + 1;
        const int ktc = 2 * i + 2;
        const bool more = (i < 7);
#pragma unroll
        for (int p = 0; p < 8; ++p) {
            const int q = p & 3, buf = p >> 2;
            const int miH = (q & 1) * 4, niH = (q >> 1) * 2;

            f16x8 af[4][2], bf[2][2];
#pragma unroll
            for (int mi = 0; mi < 4; ++mi) {
                const int o = buf * 32768 + aOff + (miH + mi) * 1024;
                af[mi][0] = *(const f16x8*)&sh[o + xk0];
                af[mi][1] = *(const f16x8*)&sh[o + xk1];
            }
#pragma unroll
            for (int ni = 0; ni < 2; ++ni) {
                const int nig = niH + ni;
                const int o = buf * 32768 + bOff + (nig & 1) * 1024 + (nig >> 1) * 8192;
                bf[ni][0] = *(const f16x8*)&sh[o + xk0];
                bf[ni][1] = *(const f16x8*)&sh[o + xk1];
            }

            if      (p == 0) STAGE_B(1, 0, ktb);
            else if (p == 1) STAGE_A(1, 0, ktb);
            else if (p == 2) STAGE_A(1, 1, ktb);
            else if (p == 3) STAGE_B(1, 1, ktb);
            else if (more) {
                if      (p == 4) STAGE_B(0, 0, ktc);
                else if (p == 5) STAGE_A(0, 0, ktc);
                else if (p == 6) STAGE_A(0, 1, ktc);
                else             STAGE_B(0, 1, ktc);
            }

            if (p < 4 || more) asm volatile("s_waitcnt vmcnt(4)" ::: "memory");
            else if (p == 4)   asm volatile("s_waitcnt vmcnt(0)" ::: "memory");
            else               asm volatile("" ::: "memory");
            __builtin_amdgcn_s_barrier();

            __builtin_amdgcn_s_setprio(1);
#pragma unroll
            for (int mi = 0; mi < 4; ++mi)
#pragma unroll
                for (int ni = 0; ni < 2; ++ni) {
                    acc[miH + mi][niH + ni] = __builtin_amdgcn_mfma_f32_16x16x32_f16(
                        af[mi][0], bf[ni][0], acc[miH + mi][niH + ni], 0, 0, 0);
                    acc[miH + mi][niH + ni] = __builtin_amdgcn_mfma_f32_16x16x32_f16(
                        af[mi][1], bf[ni][1], acc[miH + mi][niH + ni], 0, 0, 0);
                }
            __builtin_amdgcn_s_setprio(0);
            __builtin_amdgcn_s_barrier();
        }
    }

    // ---- epilogue
    const int mat = n0 >> 10;                 // 0=q 1=k 2=v
    const float* bias = (mat == 0) ? bq : (mat == 1) ? bk : bv;
    short* Out = (mat == 0) ? Qb : (mat == 1) ? Kb : Vn;
    const float s = (mat == 0) ? 0.125f * 1.4426950408889634f : 1.0f;
    const float fs = s * (1.0f / 256.0f);
    const int nm0 = n0 & 1023;
    float bias_v[4];
#pragma unroll
    for (int ni = 0; ni < 4; ++ni) bias_v[ni] = bias[nm0 + wn * 64 + ni * 16 + l16] * s;
    const int bidx = m0 >> 10;
    const int l0   = m0 & 1023;

#pragma unroll
    for (int mi = 0; mi < 8; ++mi) {
        __syncthreads();
#pragma unroll
        for (int ni = 0; ni < 4; ++ni) {
            const int col = wn * 64 + ni * 16 + l16;
#pragma unroll
            for (int rr = 0; rr < 4; ++rr) {
                const int srow = wm * 16 + quad * 4 + rr;
                sh[srow * 268 + col] =
                    (short)(unsigned short)bf16_rne(fmaf(acc[mi][ni][rr], fs, bias_v[ni]));
            }
        }
        __syncthreads();
        const int srw = t >> 4;              // 0..31
        const int c0  = (t & 15) * 16;       // 0..240
        uint4 v0 = *(uint4*)&sh[srw * 268 + c0];
        uint4 v1 = *(uint4*)&sh[srw * 268 + c0 + 8];
        const int wmS = srw >> 4, rloc = srw & 15;
        const int l = l0 + wmS * 128 + mi * 16 + rloc;
        const int nm = nm0 + c0;
        const int head = nm >> 6, d0 = nm & 63;
        short* pDst = Out + ((size_t)(bidx * HEADS + head) * 1024 + l) * 64 + d0;
        *(uint4*)pDst = v0;
        *(uint4*)(pDst + 8) = v1;
    }
}

// ---------------------------------------------------------------------------
// Kernel 1b: V transpose  [bh][l][d] -> [bh][d][l]  (bf16, conflict-free).
// ---------------------------------------------------------------------------
__global__ __launch_bounds__(256)
void vtrans(const short* __restrict__ Vn, short* __restrict__ Vt)
{
    __shared__ int tile[64 * 65];
    const int t  = threadIdx.x;
    const int lt = blockIdx.x;   // 0..15
    const int bh = blockIdx.y;   // 0..127
    const int lq = t >> 3, dc = (t & 7) * 8;
    const short* src = Vn + ((size_t)bh * 1024 + lt * 64) * 64;
#pragma unroll
    for (int h = 0; h < 2; ++h) {
        const int l = lq + h * 32;
        union { uint4 v; unsigned short us[8]; } ld;
        ld.v = *(const uint4*)&src[l * 64 + dc];
#pragma unroll
        for (int j = 0; j < 8; ++j) tile[(dc + j) * 65 + l] = ld.us[j];
    }
    __syncthreads();
    const int dr = t >> 3, lblk = (t & 7) * 8;
    short* dst = Vt + (size_t)bh * 64 * 1024 + lt * 64;
#pragma unroll
    for (int h = 0; h < 2; ++h) {
        const int d = dr + h * 32;
        union { uint4 v; unsigned short us[8]; } o;
#pragma unroll
        for (int j = 0; j < 8; ++j) o.us[j] = (unsigned short)tile[d * 65 + lblk + j];
        *(uint4*)&dst[(size_t)d * 1024 + lblk] = o.v;
    }
}

// ---------------------------------------------------------------------------
// Kernel 2: MFMA flash attention, S^T form, ZERO-SHUFFLE P, QBLK=128.
//   Each block handles 128 q rows (two 64-row sub-tiles u=0,1): halves K/V
//   HBM traffic and halves barrier drains per unit work, with the PROVEN
//   sync structure untouched (prefetch at top, ONE __syncthreads per kt).
//   LDS: K dbuf 16K | V dbuf 16K | Q 16K (Os overlays Q after main loop).
//   K staged with rows bit-permuted (prow) so QK^T C-rows land exactly in
//   PV's B-fragment key slots.  Fixed softmax reference m=0 (exp2 domain).
//   XCD swizzle: 1024 blocks, per XCD 16 bh x 8 qt (qt fastest).
// ---------------------------------------------------------------------------
__global__ __launch_bounds__(256)
void attn_mfma(const short* __restrict__ Qb, const short* __restrict__ Kb,
               const short* __restrict__ Vt, float* __restrict__ out)
{
    __shared__ short smem[25088];   // K 0..8191 | V 8192..16383 | Q 16384..24575 | (Os 16384.. as f32)

    const int t  = threadIdx.x;
    const int id  = blockIdx.x;                  // 0..1023
    const int xcd = id & 7;
    const int loc = id >> 3;                     // 0..127
    const int bh  = xcd * 16 + (loc >> 3);       // 0..127
    const int qt  = loc & 7;                     // 0..7 (128 q rows each)
    const int lane = t & 63, quad = lane >> 4, l16 = lane & 15;
    const int w = t >> 6;
    const int srow = t & 63, schunk = t >> 6;

    // prow = [b4 | b3 b2 | b5 | b1 b0] of srow -> C-layout rows == PV B-slots
    const int prow = ((srow >> 4) & 1) * 32 + ((srow >> 2) & 3) * 8
                   + (srow >> 5) * 4 + (srow & 3);

    {
#pragma unroll
        for (int u = 0; u < 2; ++u) {
            const short* gq = Qb + ((size_t)bh * 1024 + qt * 128 + u * 64 + srow) * 64 + schunk * 8;
            __builtin_amdgcn_global_load_lds((const AS1 void*)gq,        (AS3 void*)&smem[16384 + u * 4096 + t * 8],         16, 0, 0);
            __builtin_amdgcn_global_load_lds((const AS1 void*)(gq + 32), (AS3 void*)&smem[16384 + u * 4096 + (t + 256) * 8], 16, 0, 0);
        }
        const short* gk = Kb + ((size_t)bh * 1024 + prow) * 64 + schunk * 8;
        __builtin_amdgcn_global_load_lds((const AS1 void*)gk,        (AS3 void*)&smem[t * 8],         16, 0, 0);
        __builtin_amdgcn_global_load_lds((const AS1 void*)(gk + 32), (AS3 void*)&smem[(t + 256) * 8], 16, 0, 0);
        const short* gv = Vt + ((size_t)bh * 64 + srow) * 1024 + schunk * 8;
        __builtin_amdgcn_global_load_lds((const AS1 void*)gv,        (AS3 void*)&smem[8192 + t * 8],         16, 0, 0);
        __builtin_amdgcn_global_load_lds((const AS1 void*)(gv + 32), (AS3 void*)&smem[8192 + (t + 256) * 8], 16, 0, 0);
    }
    __syncthreads();

    bf16x8 qfrag[2][2];
#pragma unroll
    for (int u = 0; u < 2; ++u)
#pragma unroll
        for (int kh = 0; kh < 2; ++kh)
            qfrag[u][kh] = *(const bf16x8*)&smem[16384 + u * 4096 + ((quad + 4 * kh) * 64 + w * 16 + l16) * 8];

    f32x4 O[2][4];
#pragma unroll
    for (int u = 0; u < 2; ++u)
#pragma unroll
        for (int i = 0; i < 4; ++i) O[u][i] = (f32x4){0.f, 0.f, 0.f, 0.f};
    float l_i[2] = {0.f, 0.f};

    for (int kt = 0; kt < 16; ++kt) {
        const int cur = kt & 1, nxt = cur ^ 1;
        if (kt < 15) {
            const short* gk = Kb + ((size_t)bh * 1024 + (kt + 1) * 64 + prow) * 64 + schunk * 8;
            __builtin_amdgcn_global_load_lds((const AS1 void*)gk,        (AS3 void*)&smem[nxt * 4096 + t * 8],         16, 0, 0);
            __builtin_amdgcn_global_load_lds((const AS1 void*)(gk + 32), (AS3 void*)&smem[nxt * 4096 + (t + 256) * 8], 16, 0, 0);
            const short* gv = Vt + ((size_t)bh * 64 + srow) * 1024 + (kt + 1) * 64 + schunk * 8;
            __builtin_amdgcn_global_load_lds((const AS1 void*)gv,        (AS3 void*)&smem[8192 + nxt * 4096 + t * 8],         16, 0, 0);
            __builtin_amdgcn_global_load_lds((const AS1 void*)(gv + 32), (AS3 void*)&smem[8192 + nxt * 4096 + (t + 256) * 8], 16, 0, 0);
        }

        const short* Kc = &smem[cur * 4096];
        const short* Vc = &smem[8192 + cur * 4096];

#pragma unroll
        for (int u = 0; u < 2; ++u) {
            f32x4 ST[4];
#pragma unroll
            for (int mi = 0; mi < 4; ++mi) ST[mi] = (f32x4){0.f, 0.f, 0.f, 0.f};
            __builtin_amdgcn_s_setprio(1);
#pragma unroll
            for (int kh = 0; kh < 2; ++kh)
#pragma unroll
                for (int mi = 0; mi < 4; ++mi) {
                    const bf16x8 ka = *(const bf16x8*)&Kc[((quad + 4 * kh) * 64 + mi * 16 + l16) * 8];
                    ST[mi] = __builtin_amdgcn_mfma_f32_16x16x32_bf16(ka, qfrag[u][kh], ST[mi], 0, 0, 0);
                }
            __builtin_amdgcn_s_setprio(0);

            // softmax numerator, fixed reference m=0 (exp2 domain, |s| ~ O(4))
            float p[4][4];
            float rs = 0.f;
#pragma unroll
            for (int mi = 0; mi < 4; ++mi)
#pragma unroll
                for (int rr = 0; rr < 4; ++rr) { p[mi][rr] = EXP2F(ST[mi][rr]); rs += p[mi][rr]; }
            l_i[u] += rs;

            // zero-shuffle pack: lane already holds its PV B-fragment keys.
            union { unsigned uu[4]; bf16x8 v; } pa[2];
#pragma unroll
            for (int kh = 0; kh < 2; ++kh) {
                asm("v_cvt_pk_bf16_f32 %0, %1, %2" : "=v"(pa[kh].uu[0]) : "v"(p[kh][0]),     "v"(p[kh][1]));
                asm("v_cvt_pk_bf16_f32 %0, %1, %2" : "=v"(pa[kh].uu[1]) : "v"(p[kh][2]),     "v"(p[kh][3]));
                asm("v_cvt_pk_bf16_f32 %0, %1, %2" : "=v"(pa[kh].uu[2]) : "v"(p[kh + 2][0]), "v"(p[kh + 2][1]));
                asm("v_cvt_pk_bf16_f32 %0, %1, %2" : "=v"(pa[kh].uu[3]) : "v"(p[kh + 2][2]), "v"(p[kh + 2][3]));
            }

            __builtin_amdgcn_s_setprio(1);
#pragma unroll
            for (int kh = 0; kh < 2; ++kh)
#pragma unroll
                for (int mi = 0; mi < 4; ++mi) {
                    const bf16x8 va = *(const bf16x8*)&Vc[((quad + 4 * kh) * 64 + mi * 16 + l16) * 8];
                    O[u][mi] = __builtin_amdgcn_mfma_f32_16x16x32_bf16(va, pa[kh].v, O[u][mi], 0, 0, 0);
                }
            __builtin_amdgcn_s_setprio(0);
        }

        __syncthreads();
    }

    // complete l_i over the key dim (quad groups)
#pragma unroll
    for (int u = 0; u < 2; ++u) {
        l_i[u] += __shfl_xor(l_i[u], 16);
        l_i[u] += __shfl_xor(l_i[u], 32);
    }

    // Os slab (64 q x 68 f32) overlays the Q region; two passes (u=0,1)
    float* Os = (float*)&smem[16384];
#pragma unroll
    for (int u = 0; u < 2; ++u) {
        __syncthreads();
        const float inv = 1.0f / l_i[u];
#pragma unroll
        for (int mi = 0; mi < 4; ++mi) {
            f32x4 v;
#pragma unroll
            for (int rr = 0; rr < 4; ++rr) v[rr] = O[u][mi][rr] * inv;
            *(f32x4*)&Os[(w * 16 + l16) * 68 + mi * 16 + quad * 4] = v;
        }
        __syncthreads();
        const int q = t >> 2, dbase = (t & 3) * 16;
        float* op = out + ((size_t)bh * 1024 + qt * 128 + u * 64 + q) * 64 + dbase;
#pragma unroll
        for (int i = 0; i < 4; ++i)
            *(float4*)&op[i * 4] = *(float4*)&Os[q * 68 + dbase + i * 4];
    }
}

extern "C" void kernel_launch(void* const* d_in, const int* in_sizes, int n_in,
                              void* d_out, int out_size, void* d_ws, size_t ws_size,
                              hipStream_t stream)
{
    const float* X  = (const float*)d_in[0];
    const float* Wq = (const float*)d_in[1];
    const float* bq = (const float*)d_in[2];
    const float* Wk = (const float*)d_in[3];
    const float* bk = (const float*)d_in[4];
    const float* Wv = (const float*)d_in[5];
    const float* bv = (const float*)d_in[6];
    float* out = (float*)d_out;

    const size_t per = (size_t)8 * HEADS * 1024 * HDIM;   // 8,388,608
    short* Qb = (short*)d_ws;
    short* Kb = Qb + per;
    short* Vt = Kb + per;
    short* Xh = Vt + per;                 // fp16
    short* Wh = Xh + per;                 // fp16 (x256), 3 x 1,048,576
    short* Vn = (short*)d_out;            // scratch: V natural layout (overwritten by attn)

    cast_all<<<4096 + 3 * 512, 256, 0, stream>>>(X, Wq, Wk, Wv, Xh, Wh);

    qkv_mfma<<<dim3(12, 32), 512, 0, stream>>>(Xh, Wh, bq, bk, bv, Qb, Kb, Vn);
    vtrans<<<dim3(16, 128), 256, 0, stream>>>(Vn, Vt);
    attn_mfma<<<1024, 256, 0, stream>>>(Qb, Kb, Vt, out);
}

// Round 8
// 214.823 us; speedup vs baseline: 1.1842x; 1.0655x over previous
//
#include <hip/hip_runtime.h>

#define EMBED 1024
#define HEADS 16
#define HDIM  64

typedef __attribute__((ext_vector_type(8))) short bf16x8;
typedef __attribute__((ext_vector_type(8))) _Float16 f16x8;
typedef __attribute__((ext_vector_type(4))) float f32x4;

#define AS1 __attribute__((address_space(1)))
#define AS3 __attribute__((address_space(3)))

#if __has_builtin(__builtin_amdgcn_exp2f)
#define EXP2F(x) __builtin_amdgcn_exp2f(x)
#else
#define EXP2F(x) exp2f(x)
#endif

__device__ __forceinline__ unsigned bf16_rne(float f) {
    unsigned u = __float_as_uint(f);
    return (u + 0x7FFFu + ((u >> 16) & 1u)) >> 16;
}

// ---------------------------------------------------------------------------
// Kernel 0: fused cast fp32 -> fp16 (RNE) for X (scale 1) and Wq/Wk/Wv
// (scale 256, undone in GEMM epilogue).
// ---------------------------------------------------------------------------
__global__ __launch_bounds__(256)
void cast_all(const float* __restrict__ X,  const float* __restrict__ Wq,
              const float* __restrict__ Wk, const float* __restrict__ Wv,
              short* __restrict__ Xh, short* __restrict__ Wh)
{
    const int bid = blockIdx.x;
    const float* in;
    short* out;
    float scale;
    int base;
    if (bid < 4096) { in = X; out = Xh; scale = 1.0f; base = bid; }
    else {
        const int wsel = (bid - 4096) >> 9;        // 0..2
        in  = (wsel == 0) ? Wq : (wsel == 1) ? Wk : Wv;
        out = Wh + wsel * 1048576;
        scale = 256.0f;
        base = (bid - 4096) & 511;
    }
    const int i = (base * 256 + threadIdx.x) * 8;
    float4 a = *(const float4*)(in + i);
    float4 b = *(const float4*)(in + i + 4);
    float f[8] = {a.x, a.y, a.z, a.w, b.x, b.y, b.z, b.w};
    union { _Float16 h[8]; uint4 v; } H;
#pragma unroll
    for (int e = 0; e < 8; ++e) H.h[e] = (_Float16)(f[e] * scale);
    *(uint4*)(out + i) = H.v;
}

// ---------------------------------------------------------------------------
// Kernel 1: QKV projection -- proven 256x256 / BK=64 / 8-wave / 8-phase loop
// (unchanged).  NEW: V panels write a TRANSPOSED epilogue slab and store
// directly to Vt[bh][d][l] (coalesced 32B runs) -- vtrans kernel eliminated.
// ---------------------------------------------------------------------------
#define STAGE_A(buf, h, kt) do {                                              \
    const short* s0_ = baseA + ((h) * 128) * EMBED + (kt) * 64;               \
    short* d_ = &sh[(buf) * 32768 + (h) * 8192 + t * 8];                      \
    __builtin_amdgcn_global_load_lds((const AS1 void*)s0_, (AS3 void*)d_, 16, 0, 0); \
    __builtin_amdgcn_global_load_lds((const AS1 void*)(s0_ + 64 * EMBED), (AS3 void*)(d_ + 4096), 16, 0, 0); \
} while (0)

#define STAGE_B(buf, h, kt) do {                                              \
    const short* s0_ = baseB + ((h) * 32) * EMBED + (kt) * 64;                \
    short* d_ = &sh[(buf) * 32768 + 16384 + (h) * 8192 + t * 8];              \
    __builtin_amdgcn_global_load_lds((const AS1 void*)s0_, (AS3 void*)d_, 16, 0, 0); \
    __builtin_amdgcn_global_load_lds((const AS1 void*)(s0_ + 128 * EMBED), (AS3 void*)(d_ + 4096), 16, 0, 0); \
} while (0)

__global__ __launch_bounds__(512, 2)
void qkv_mfma(const short* __restrict__ Xh, const short* __restrict__ Wh,
              const float* __restrict__ bq, const float* __restrict__ bk,
              const float* __restrict__ bv,
              short* __restrict__ Qb, short* __restrict__ Kb, short* __restrict__ Vt)
{
    __shared__ short sh[65536];   // 128 KiB

    const int t = threadIdx.x;
    const int lane = t & 63, quad = lane >> 4, l16 = lane & 15;
    const int w = t >> 6, wm = w >> 2, wn = w & 3;

    const int n0 = blockIdx.x * 256;   // 0..11 -> Q/K/V column panel
    const int m0 = blockIdx.y * 256;   // 0..31

    const int r  = t >> 3;                       // 0..63
    const int k8 = ((t & 7) ^ (r & 7)) * 8;      // swizzled k element offset
    const short* baseA = Xh + (size_t)(m0 + r) * EMBED + k8;
    const short* baseB = Wh + (size_t)(n0 + (r & 31) + (r >> 5) * 64) * EMBED + k8;

    const int xk0 = ((quad * 16)      ^ ((l16 & 7) << 4)) >> 1;  // ks=0
    const int xk1 = ((64 + quad * 16) ^ ((l16 & 7) << 4)) >> 1;  // ks=1
    const int aOff = wm * 8192 + l16 * 64;                 // + mi*1024
    const int bOff = 16384 + wn * 2048 + l16 * 64;

    f32x4 acc[8][4];
#pragma unroll
    for (int i = 0; i < 8; ++i)
#pragma unroll
        for (int j = 0; j < 4; ++j) acc[i][j] = (f32x4){0.f, 0.f, 0.f, 0.f};

    STAGE_B(0, 0, 0);
    STAGE_A(0, 0, 0);
    STAGE_A(0, 1, 0);
    STAGE_B(0, 1, 0);
    asm volatile("s_waitcnt vmcnt(4)" ::: "memory");
    __builtin_amdgcn_s_barrier();

#pragma unroll 1
    for (int i = 0; i < 8; ++i) {
        const int ktb = 2 * i + 1;
        const int ktc = 2 * i + 2;
        const bool more = (i < 7);
#pragma unroll
        for (int p = 0; p < 8; ++p) {
            const int q = p & 3, buf = p >> 2;
            const int miH = (q & 1) * 4, niH = (q >> 1) * 2;

            f16x8 af[4][2], bf[2][2];
#pragma unroll
            for (int mi = 0; mi < 4; ++mi) {
                const int o = buf * 32768 + aOff + (miH + mi) * 1024;
                af[mi][0] = *(const f16x8*)&sh[o + xk0];
                af[mi][1] = *(const f16x8*)&sh[o + xk1];
            }
#pragma unroll
            for (int ni = 0; ni < 2; ++ni) {
                const int nig = niH + ni;
                const int o = buf * 32768 + bOff + (nig & 1) * 1024 + (nig >> 1) * 8192;
                bf[ni][0] = *(const f16x8*)&sh[o + xk0];
                bf[ni][1] = *(const f16x8*)&sh[o + xk1];
            }

            if      (p == 0) STAGE_B(1, 0, ktb);
            else if (p == 1) STAGE_A(1, 0, ktb);
            else if (p == 2) STAGE_A(1, 1, ktb);
            else if (p == 3) STAGE_B(1, 1, ktb);
            else if (more) {
                if      (p == 4) STAGE_B(0, 0, ktc);
                else if (p == 5) STAGE_A(0, 0, ktc);
                else if (p == 6) STAGE_A(0, 1, ktc);
                else             STAGE_B(0, 1, ktc);
            }

            if (p < 4 || more) asm volatile("s_waitcnt vmcnt(4)" ::: "memory");
            else if (p == 4)   asm volatile("s_waitcnt vmcnt(0)" ::: "memory");
            else               asm volatile("" ::: "memory");
            __builtin_amdgcn_s_barrier();

            __builtin_amdgcn_s_setprio(1);
#pragma unroll
            for (int mi = 0; mi < 4; ++mi)
#pragma unroll
                for (int ni = 0; ni < 2; ++ni) {
                    acc[miH + mi][niH + ni] = __builtin_amdgcn_mfma_f32_16x16x32_f16(
                        af[mi][0], bf[ni][0], acc[miH + mi][niH + ni], 0, 0, 0);
                    acc[miH + mi][niH + ni] = __builtin_amdgcn_mfma_f32_16x16x32_f16(
                        af[mi][1], bf[ni][1], acc[miH + mi][niH + ni], 0, 0, 0);
                }
            __builtin_amdgcn_s_setprio(0);
            __builtin_amdgcn_s_barrier();
        }
    }

    // ---- epilogue
    const int mat = n0 >> 10;                 // 0=q 1=k 2=v
    const float* bias = (mat == 0) ? bq : (mat == 1) ? bk : bv;
    const float s = (mat == 0) ? 0.125f * 1.4426950408889634f : 1.0f;
    const float fs = s * (1.0f / 256.0f);
    const int nm0 = n0 & 1023;
    float bias_v[4];
#pragma unroll
    for (int ni = 0; ni < 4; ++ni) bias_v[ni] = bias[nm0 + wn * 64 + ni * 16 + l16] * s;
    const int bidx = m0 >> 10;
    const int l0   = m0 & 1023;

    if (mat == 2) {
        // ---- fused V-transpose epilogue: slab [256 nm][pad 40] x 32 l
        //      then coalesced 32B stores to Vt[bh][d][l].
#pragma unroll
        for (int mi = 0; mi < 8; ++mi) {
            __syncthreads();
#pragma unroll
            for (int ni = 0; ni < 4; ++ni) {
                const int col = wn * 64 + ni * 16 + l16;
                union { unsigned short us[4]; uint2 v; } pk;
#pragma unroll
                for (int rr = 0; rr < 4; ++rr)
                    pk.us[rr] = (unsigned short)bf16_rne(fmaf(acc[mi][ni][rr], fs, bias_v[ni]));
                *(uint2*)&sh[col * 40 + wm * 16 + quad * 4] = pk.v;   // 4 l-values
            }
            __syncthreads();
            const int nm  = t & 255;             // 0..255 (local col)
            const int wmS = t >> 8;              // 0..1
            uint4 v0 = *(uint4*)&sh[nm * 40 + wmS * 16];
            uint4 v1 = *(uint4*)&sh[nm * 40 + wmS * 16 + 8];
            const int nmg = nm0 + nm;
            const int head = nmg >> 6, d0v = nmg & 63;
            const int l = l0 + wmS * 128 + mi * 16;
            short* pDst = Vt + ((size_t)(bidx * HEADS + head) * 64 + d0v) * 1024 + l;
            *(uint4*)pDst = v0;
            *(uint4*)(pDst + 8) = v1;
        }
        return;
    }

    short* Out = (mat == 0) ? Qb : Kb;
#pragma unroll
    for (int mi = 0; mi < 8; ++mi) {
        __syncthreads();
#pragma unroll
        for (int ni = 0; ni < 4; ++ni) {
            const int col = wn * 64 + ni * 16 + l16;
#pragma unroll
            for (int rr = 0; rr < 4; ++rr) {
                const int srow = wm * 16 + quad * 4 + rr;
                sh[srow * 268 + col] =
                    (short)(unsigned short)bf16_rne(fmaf(acc[mi][ni][rr], fs, bias_v[ni]));
            }
        }
        __syncthreads();
        const int srw = t >> 4;              // 0..31
        const int c0  = (t & 15) * 16;       // 0..240
        uint4 v0 = *(uint4*)&sh[srw * 268 + c0];
        uint4 v1 = *(uint4*)&sh[srw * 268 + c0 + 8];
        const int wmS = srw >> 4, rloc = srw & 15;
        const int l = l0 + wmS * 128 + mi * 16 + rloc;
        const int nm = nm0 + c0;
        const int head = nm >> 6, d0 = nm & 63;
        short* pDst = Out + ((size_t)(bidx * HEADS + head) * 1024 + l) * 64 + d0;
        *(uint4*)pDst = v0;
        *(uint4*)(pDst + 8) = v1;
    }
}

// ---------------------------------------------------------------------------
// Kernel 2: MFMA flash attention, S^T form, ZERO-SHUFFLE P, QBLK=256.
//   Each block handles 256 q rows (four 64-row sub-tiles u=0..3): quarters
//   K/V traffic and amortizes each kt drain over 64 MFMA, with the PROVEN
//   sync structure untouched (prefetch at top, ONE __syncthreads per kt).
//   LDS 64 KiB: K dbuf 16K | V dbuf 16K | Q 32K (Os overlays Q after loop).
//   Grid 512 = 2 blocks/CU -> ALL blocks co-resident, zero dispatch tail.
//   K staged with rows bit-permuted (prow) so QK^T C-rows land exactly in
//   PV's B-fragment key slots.  Fixed softmax reference m=0 (exp2 domain).
//   XCD swizzle: per XCD 16 bh x 4 qt (qt fastest).
// ---------------------------------------------------------------------------
__global__ __launch_bounds__(256, 2)
void attn_mfma(const short* __restrict__ Qb, const short* __restrict__ Kb,
               const short* __restrict__ Vt, float* __restrict__ out)
{
    __shared__ short smem[32768];   // K 0..8191 | V 8192..16383 | Q 16384..32767

    const int t  = threadIdx.x;
    const int id  = blockIdx.x;                  // 0..511
    const int xcd = id & 7;
    const int loc = id >> 3;                     // 0..63
    const int bh  = xcd * 16 + (loc >> 2);       // 0..127
    const int qt  = loc & 3;                     // 0..3 (256 q rows each)
    const int lane = t & 63, quad = lane >> 4, l16 = lane & 15;
    const int w = t >> 6;
    const int srow = t & 63, schunk = t >> 6;

    // prow = [b4 | b3 b2 | b5 | b1 b0] of srow -> C-layout rows == PV B-slots
    const int prow = ((srow >> 4) & 1) * 32 + ((srow >> 2) & 3) * 8
                   + (srow >> 5) * 4 + (srow & 3);

    {
#pragma unroll
        for (int u = 0; u < 4; ++u) {
            const short* gq = Qb + ((size_t)bh * 1024 + qt * 256 + u * 64 + srow) * 64 + schunk * 8;
            __builtin_amdgcn_global_load_lds((const AS1 void*)gq,        (AS3 void*)&smem[16384 + u * 4096 + t * 8],         16, 0, 0);
            __builtin_amdgcn_global_load_lds((const AS1 void*)(gq + 32), (AS3 void*)&smem[16384 + u * 4096 + (t + 256) * 8], 16, 0, 0);
        }
        const short* gk = Kb + ((size_t)bh * 1024 + prow) * 64 + schunk * 8;
        __builtin_amdgcn_global_load_lds((const AS1 void*)gk,        (AS3 void*)&smem[t * 8],         16, 0, 0);
        __builtin_amdgcn_global_load_lds((const AS1 void*)(gk + 32), (AS3 void*)&smem[(t + 256) * 8], 16, 0, 0);
        const short* gv = Vt + ((size_t)bh * 64 + srow) * 1024 + schunk * 8;
        __builtin_amdgcn_global_load_lds((const AS1 void*)gv,        (AS3 void*)&smem[8192 + t * 8],         16, 0, 0);
        __builtin_amdgcn_global_load_lds((const AS1 void*)(gv + 32), (AS3 void*)&smem[8192 + (t + 256) * 8], 16, 0, 0);
    }
    __syncthreads();

    bf16x8 qfrag[4][2];
#pragma unroll
    for (int u = 0; u < 4; ++u)
#pragma unroll
        for (int kh = 0; kh < 2; ++kh)
            qfrag[u][kh] = *(const bf16x8*)&smem[16384 + u * 4096 + ((quad + 4 * kh) * 64 + w * 16 + l16) * 8];

    f32x4 O[4][4];
#pragma unroll
    for (int u = 0; u < 4; ++u)
#pragma unroll
        for (int i = 0; i < 4; ++i) O[u][i] = (f32x4){0.f, 0.f, 0.f, 0.f};
    float l_i[4] = {0.f, 0.f, 0.f, 0.f};

    for (int kt = 0; kt < 16; ++kt) {
        const int cur = kt & 1, nxt = cur ^ 1;
        if (kt < 15) {
            const short* gk = Kb + ((size_t)bh * 1024 + (kt + 1) * 64 + prow) * 64 + schunk * 8;
            __builtin_amdgcn_global_load_lds((const AS1 void*)gk,        (AS3 void*)&smem[nxt * 4096 + t * 8],         16, 0, 0);
            __builtin_amdgcn_global_load_lds((const AS1 void*)(gk + 32), (AS3 void*)&smem[nxt * 4096 + (t + 256) * 8], 16, 0, 0);
            const short* gv = Vt + ((size_t)bh * 64 + srow) * 1024 + (kt + 1) * 64 + schunk * 8;
            __builtin_amdgcn_global_load_lds((const AS1 void*)gv,        (AS3 void*)&smem[8192 + nxt * 4096 + t * 8],         16, 0, 0);
            __builtin_amdgcn_global_load_lds((const AS1 void*)(gv + 32), (AS3 void*)&smem[8192 + nxt * 4096 + (t + 256) * 8], 16, 0, 0);
        }

        const short* Kc = &smem[cur * 4096];
        const short* Vc = &smem[8192 + cur * 4096];

#pragma unroll
        for (int u = 0; u < 4; ++u) {
            f32x4 ST[4];
#pragma unroll
            for (int mi = 0; mi < 4; ++mi) ST[mi] = (f32x4){0.f, 0.f, 0.f, 0.f};
            __builtin_amdgcn_s_setprio(1);
#pragma unroll
            for (int kh = 0; kh < 2; ++kh)
#pragma unroll
                for (int mi = 0; mi < 4; ++mi) {
                    const bf16x8 ka = *(const bf16x8*)&Kc[((quad + 4 * kh) * 64 + mi * 16 + l16) * 8];
                    ST[mi] = __builtin_amdgcn_mfma_f32_16x16x32_bf16(ka, qfrag[u][kh], ST[mi], 0, 0, 0);
                }
            __builtin_amdgcn_s_setprio(0);

            // softmax numerator, fixed reference m=0 (exp2 domain, |s| ~ O(4))
            float p[4][4];
            float rs = 0.f;
#pragma unroll
            for (int mi = 0; mi < 4; ++mi)
#pragma unroll
                for (int rr = 0; rr < 4; ++rr) { p[mi][rr] = EXP2F(ST[mi][rr]); rs += p[mi][rr]; }
            l_i[u] += rs;

            // zero-shuffle pack: lane already holds its PV B-fragment keys.
            union { unsigned uu[4]; bf16x8 v; } pa[2];
#pragma unroll
            for (int kh = 0; kh < 2; ++kh) {
                asm("v_cvt_pk_bf16_f32 %0, %1, %2" : "=v"(pa[kh].uu[0]) : "v"(p[kh][0]),     "v"(p[kh][1]));
                asm("v_cvt_pk_bf16_f32 %0, %1, %2" : "=v"(pa[kh].uu[1]) : "v"(p[kh][2]),     "v"(p[kh][3]));
                asm("v_cvt_pk_bf16_f32 %0, %1, %2" : "=v"(pa[kh].uu[2]) : "v"(p[kh + 2][0]), "v"(p[kh + 2][1]));
                asm("v_cvt_pk_bf16_f32 %0, %1, %2" : "=v"(pa[kh].uu[3]) : "v"(p[kh + 2][2]), "v"(p[kh + 2][3]));
            }

            __builtin_amdgcn_s_setprio(1);
#pragma unroll
            for (int kh = 0; kh < 2; ++kh)
#pragma unroll
                for (int mi = 0; mi < 4; ++mi) {
                    const bf16x8 va = *(const bf16x8*)&Vc[((quad + 4 * kh) * 64 + mi * 16 + l16) * 8];
                    O[u][mi] = __builtin_amdgcn_mfma_f32_16x16x32_bf16(va, pa[kh].v, O[u][mi], 0, 0, 0);
                }
            __builtin_amdgcn_s_setprio(0);
        }

        __syncthreads();
    }

    // complete l_i over the key dim (quad groups)
#pragma unroll
    for (int u = 0; u < 4; ++u) {
        l_i[u] += __shfl_xor(l_i[u], 16);
        l_i[u] += __shfl_xor(l_i[u], 32);
    }

    // Os slab (64 q x 68 f32) overlays the Q region; four passes (u=0..3)
    float* Os = (float*)&smem[16384];
#pragma unroll
    for (int u = 0; u < 4; ++u) {
        __syncthreads();
        const float inv = 1.0f / l_i[u];
#pragma unroll
        for (int mi = 0; mi < 4; ++mi) {
            f32x4 v;
#pragma unroll
            for (int rr = 0; rr < 4; ++rr) v[rr] = O[u][mi][rr] * inv;
            *(f32x4*)&Os[(w * 16 + l16) * 68 + mi * 16 + quad * 4] = v;
        }
        __syncthreads();
        const int q = t >> 2, dbase = (t & 3) * 16;
        float* op = out + ((size_t)bh * 1024 + qt * 256 + u * 64 + q) * 64 + dbase;
#pragma unroll
        for (int i = 0; i < 4; ++i)
            *(float4*)&op[i * 4] = *(float4*)&Os[q * 68 + dbase + i * 4];
    }
}

extern "C" void kernel_launch(void* const* d_in, const int* in_sizes, int n_in,
                              void* d_out, int out_size, void* d_ws, size_t ws_size,
                              hipStream_t stream)
{
    const float* X  = (const float*)d_in[0];
    const float* Wq = (const float*)d_in[1];
    const float* bq = (const float*)d_in[2];
    const float* Wk = (const float*)d_in[3];
    const float* bk = (const float*)d_in[4];
    const float* Wv = (const float*)d_in[5];
    const float* bv = (const float*)d_in[6];
    float* out = (float*)d_out;

    const size_t per = (size_t)8 * HEADS * 1024 * HDIM;   // 8,388,608
    short* Qb = (short*)d_ws;
    short* Kb = Qb + per;
    short* Vt = Kb + per;
    short* Xh = Vt + per;                 // fp16
    short* Wh = Xh + per;                 // fp16 (x256), 3 x 1,048,576

    cast_all<<<4096 + 3 * 512, 256, 0, stream>>>(X, Wq, Wk, Wv, Xh, Wh);

    qkv_mfma<<<dim3(12, 32), 512, 0, stream>>>(Xh, Wh, bq, bk, bv, Qb, Kb, Vt);
    attn_mfma<<<512, 256, 0, stream>>>(Qb, Kb, Vt, out);
}

// Round 9
// 209.800 us; speedup vs baseline: 1.2125x; 1.0239x over previous
//
#include <hip/hip_runtime.h>

#define EMBED 1024
#define HEADS 16
#define HDIM  64

typedef __attribute__((ext_vector_type(8))) short bf16x8;
typedef __attribute__((ext_vector_type(8))) _Float16 f16x8;
typedef __attribute__((ext_vector_type(4))) float f32x4;

#define AS1 __attribute__((address_space(1)))
#define AS3 __attribute__((address_space(3)))

#if __has_builtin(__builtin_amdgcn_exp2f)
#define EXP2F(x) __builtin_amdgcn_exp2f(x)
#else
#define EXP2F(x) exp2f(x)
#endif

__device__ __forceinline__ unsigned bf16_rne(float f) {
    unsigned u = __float_as_uint(f);
    return (u + 0x7FFFu + ((u >> 16) & 1u)) >> 16;
}

// ---------------------------------------------------------------------------
// Kernel 0: fused cast fp32 -> fp16 (RNE) for X (scale 1) and Wq/Wk/Wv
// (scale 256, undone in GEMM epilogue).
// ---------------------------------------------------------------------------
__global__ __launch_bounds__(256)
void cast_all(const float* __restrict__ X,  const float* __restrict__ Wq,
              const float* __restrict__ Wk, const float* __restrict__ Wv,
              short* __restrict__ Xh, short* __restrict__ Wh)
{
    const int bid = blockIdx.x;
    const float* in;
    short* out;
    float scale;
    int base;
    if (bid < 4096) { in = X; out = Xh; scale = 1.0f; base = bid; }
    else {
        const int wsel = (bid - 4096) >> 9;        // 0..2
        in  = (wsel == 0) ? Wq : (wsel == 1) ? Wk : Wv;
        out = Wh + wsel * 1048576;
        scale = 256.0f;
        base = (bid - 4096) & 511;
    }
    const int i = (base * 256 + threadIdx.x) * 8;
    float4 a = *(const float4*)(in + i);
    float4 b = *(const float4*)(in + i + 4);
    float f[8] = {a.x, a.y, a.z, a.w, b.x, b.y, b.z, b.w};
    union { _Float16 h[8]; uint4 v; } H;
#pragma unroll
    for (int e = 0; e < 8; ++e) H.h[e] = (_Float16)(f[e] * scale);
    *(uint4*)(out + i) = H.v;
}

// ---------------------------------------------------------------------------
// Kernel 1: QKV projection -- proven 256x256 / BK=64 / 8-wave / 8-phase
// skeleton (staging order, vmcnt(4) chain, barriers, grid all unchanged).
// NEW in-loop read pattern: kh-major phases.  Per kh boundary load af8[0..7]
// (all 8 mi, ONE kh) once and reuse across the two ni-half phases; per phase
// read only 2 B-frags.  LDS-read traffic per wave per K-tile: 48KB -> 24KB
// (old quadrant layout read every A/B frag twice) -> flips the phase balance
// from LDS-BW-bound to MFMA-bound.  Accum order per acc element unchanged
// (kh0 then kh1) -> bitwise-identical output.
// ---------------------------------------------------------------------------
#define STAGE_A(buf, h, kt) do {                                              \
    const short* s0_ = baseA + ((h) * 128) * EMBED + (kt) * 64;               \
    short* d_ = &sh[(buf) * 32768 + (h) * 8192 + t * 8];                      \
    __builtin_amdgcn_global_load_lds((const AS1 void*)s0_, (AS3 void*)d_, 16, 0, 0); \
    __builtin_amdgcn_global_load_lds((const AS1 void*)(s0_ + 64 * EMBED), (AS3 void*)(d_ + 4096), 16, 0, 0); \
} while (0)

#define STAGE_B(buf, h, kt) do {                                              \
    const short* s0_ = baseB + ((h) * 32) * EMBED + (kt) * 64;                \
    short* d_ = &sh[(buf) * 32768 + 16384 + (h) * 8192 + t * 8];              \
    __builtin_amdgcn_global_load_lds((const AS1 void*)s0_, (AS3 void*)d_, 16, 0, 0); \
    __builtin_amdgcn_global_load_lds((const AS1 void*)(s0_ + 128 * EMBED), (AS3 void*)(d_ + 4096), 16, 0, 0); \
} while (0)

__global__ __launch_bounds__(512, 2)
void qkv_mfma(const short* __restrict__ Xh, const short* __restrict__ Wh,
              const float* __restrict__ bq, const float* __restrict__ bk,
              const float* __restrict__ bv,
              short* __restrict__ Qb, short* __restrict__ Kb, short* __restrict__ Vt)
{
    __shared__ short sh[65536];   // 128 KiB

    const int t = threadIdx.x;
    const int lane = t & 63, quad = lane >> 4, l16 = lane & 15;
    const int w = t >> 6, wm = w >> 2, wn = w & 3;

    const int n0 = blockIdx.x * 256;   // 0..11 -> Q/K/V column panel
    const int m0 = blockIdx.y * 256;   // 0..31

    const int r  = t >> 3;                       // 0..63
    const int k8 = ((t & 7) ^ (r & 7)) * 8;      // swizzled k element offset
    const short* baseA = Xh + (size_t)(m0 + r) * EMBED + k8;
    const short* baseB = Wh + (size_t)(n0 + (r & 31) + (r >> 5) * 64) * EMBED + k8;

    const int xk0 = ((quad * 16)      ^ ((l16 & 7) << 4)) >> 1;  // ks=0
    const int xk1 = ((64 + quad * 16) ^ ((l16 & 7) << 4)) >> 1;  // ks=1
    const int aOff = wm * 8192 + l16 * 64;                 // + mi*1024
    const int bOff = 16384 + wn * 2048 + l16 * 64;

    f32x4 acc[8][4];
#pragma unroll
    for (int i = 0; i < 8; ++i)
#pragma unroll
        for (int j = 0; j < 4; ++j) acc[i][j] = (f32x4){0.f, 0.f, 0.f, 0.f};

    STAGE_B(0, 0, 0);
    STAGE_A(0, 0, 0);
    STAGE_A(0, 1, 0);
    STAGE_B(0, 1, 0);
    asm volatile("s_waitcnt vmcnt(4)" ::: "memory");
    __builtin_amdgcn_s_barrier();

#pragma unroll 1
    for (int i = 0; i < 8; ++i) {
        const int ktb = 2 * i + 1;
        const int ktc = 2 * i + 2;
        const bool more = (i < 7);
        f16x8 af8[8];
#pragma unroll
        for (int p = 0; p < 8; ++p) {
            const int q = p & 3, buf = p >> 2;
            const int kh  = q >> 1;           // kh0,kh0,kh1,kh1
            const int nih = (q & 1) * 2;      // 0,2,0,2
            const int xk  = kh ? xk1 : xk0;

            // A frags: all 8 mi once per kh (reused across both ni-phases)
            if (nih == 0) {
#pragma unroll
                for (int mi = 0; mi < 8; ++mi)
                    af8[mi] = *(const f16x8*)&sh[buf * 32768 + aOff + mi * 1024 + xk];
            }
            f16x8 bf[2];
#pragma unroll
            for (int ni = 0; ni < 2; ++ni) {
                const int nig = nih + ni;
                bf[ni] = *(const f16x8*)&sh[buf * 32768 + bOff + (nig & 1) * 1024 + (nig >> 1) * 8192 + xk];
            }

            if      (p == 0) STAGE_B(1, 0, ktb);
            else if (p == 1) STAGE_A(1, 0, ktb);
            else if (p == 2) STAGE_A(1, 1, ktb);
            else if (p == 3) STAGE_B(1, 1, ktb);
            else if (more) {
                if      (p == 4) STAGE_B(0, 0, ktc);
                else if (p == 5) STAGE_A(0, 0, ktc);
                else if (p == 6) STAGE_A(0, 1, ktc);
                else             STAGE_B(0, 1, ktc);
            }

            if (p < 4 || more) asm volatile("s_waitcnt vmcnt(4)" ::: "memory");
            else if (p == 4)   asm volatile("s_waitcnt vmcnt(0)" ::: "memory");
            else               asm volatile("" ::: "memory");
            __builtin_amdgcn_s_barrier();

            __builtin_amdgcn_s_setprio(1);
#pragma unroll
            for (int mi = 0; mi < 8; ++mi)
#pragma unroll
                for (int ni = 0; ni < 2; ++ni)
                    acc[mi][nih + ni] = __builtin_amdgcn_mfma_f32_16x16x32_f16(
                        af8[mi], bf[ni], acc[mi][nih + ni], 0, 0, 0);
            __builtin_amdgcn_s_setprio(0);
            __builtin_amdgcn_s_barrier();
        }
    }

    // ---- epilogue
    const int mat = n0 >> 10;                 // 0=q 1=k 2=v
    const float* bias = (mat == 0) ? bq : (mat == 1) ? bk : bv;
    const float s = (mat == 0) ? 0.125f * 1.4426950408889634f : 1.0f;
    const float fs = s * (1.0f / 256.0f);
    const int nm0 = n0 & 1023;
    float bias_v[4];
#pragma unroll
    for (int ni = 0; ni < 4; ++ni) bias_v[ni] = bias[nm0 + wn * 64 + ni * 16 + l16] * s;
    const int bidx = m0 >> 10;
    const int l0   = m0 & 1023;

    if (mat == 2) {
        // ---- fused V-transpose epilogue: slab [256 nm][pad 40] x 32 l
        //      then coalesced 32B stores to Vt[bh][d][l].
#pragma unroll
        for (int mi = 0; mi < 8; ++mi) {
            __syncthreads();
#pragma unroll
            for (int ni = 0; ni < 4; ++ni) {
                const int col = wn * 64 + ni * 16 + l16;
                union { unsigned short us[4]; uint2 v; } pk;
#pragma unroll
                for (int rr = 0; rr < 4; ++rr)
                    pk.us[rr] = (unsigned short)bf16_rne(fmaf(acc[mi][ni][rr], fs, bias_v[ni]));
                *(uint2*)&sh[col * 40 + wm * 16 + quad * 4] = pk.v;   // 4 l-values
            }
            __syncthreads();
            const int nm  = t & 255;             // 0..255 (local col)
            const int wmS = t >> 8;              // 0..1
            uint4 v0 = *(uint4*)&sh[nm * 40 + wmS * 16];
            uint4 v1 = *(uint4*)&sh[nm * 40 + wmS * 16 + 8];
            const int nmg = nm0 + nm;
            const int head = nmg >> 6, d0v = nmg & 63;
            const int l = l0 + wmS * 128 + mi * 16;
            short* pDst = Vt + ((size_t)(bidx * HEADS + head) * 64 + d0v) * 1024 + l;
            *(uint4*)pDst = v0;
            *(uint4*)(pDst + 8) = v1;
        }
        return;
    }

    short* Out = (mat == 0) ? Qb : Kb;
#pragma unroll
    for (int mi = 0; mi < 8; ++mi) {
        __syncthreads();
#pragma unroll
        for (int ni = 0; ni < 4; ++ni) {
            const int col = wn * 64 + ni * 16 + l16;
#pragma unroll
            for (int rr = 0; rr < 4; ++rr) {
                const int srow = wm * 16 + quad * 4 + rr;
                sh[srow * 268 + col] =
                    (short)(unsigned short)bf16_rne(fmaf(acc[mi][ni][rr], fs, bias_v[ni]));
            }
        }
        __syncthreads();
        const int srw = t >> 4;              // 0..31
        const int c0  = (t & 15) * 16;       // 0..240
        uint4 v0 = *(uint4*)&sh[srw * 268 + c0];
        uint4 v1 = *(uint4*)&sh[srw * 268 + c0 + 8];
        const int wmS = srw >> 4, rloc = srw & 15;
        const int l = l0 + wmS * 128 + mi * 16 + rloc;
        const int nm = nm0 + c0;
        const int head = nm >> 6, d0 = nm & 63;
        short* pDst = Out + ((size_t)(bidx * HEADS + head) * 1024 + l) * 64 + d0;
        *(uint4*)pDst = v0;
        *(uint4*)(pDst + 8) = v1;
    }
}

// ---------------------------------------------------------------------------
// Kernel 2: MFMA flash attention, S^T form, ZERO-SHUFFLE P, QBLK=256.
//   Proven structure (prefetch at top, ONE __syncthreads per kt), four
//   64-row q sub-tiles per block.  LDS 64 KiB: K dbuf | V dbuf | Q (Os
//   overlays Q).  Grid 512 = 2 blocks/CU, zero dispatch tail.
//   K staged with rows bit-permuted (prow) so QK^T C-rows land exactly in
//   PV's B-fragment key slots.  Fixed softmax reference m=0 (exp2 domain).
//   XCD swizzle: per XCD 16 bh x 4 qt (qt fastest).
// ---------------------------------------------------------------------------
__global__ __launch_bounds__(256, 2)
void attn_mfma(const short* __restrict__ Qb, const short* __restrict__ Kb,
               const short* __restrict__ Vt, float* __restrict__ out)
{
    __shared__ short smem[32768];   // K 0..8191 | V 8192..16383 | Q 16384..32767

    const int t  = threadIdx.x;
    const int id  = blockIdx.x;                  // 0..511
    const int xcd = id & 7;
    const int loc = id >> 3;                     // 0..63
    const int bh  = xcd * 16 + (loc >> 2);       // 0..127
    const int qt  = loc & 3;                     // 0..3 (256 q rows each)
    const int lane = t & 63, quad = lane >> 4, l16 = lane & 15;
    const int w = t >> 6;
    const int srow = t & 63, schunk = t >> 6;

    // prow = [b4 | b3 b2 | b5 | b1 b0] of srow -> C-layout rows == PV B-slots
    const int prow = ((srow >> 4) & 1) * 32 + ((srow >> 2) & 3) * 8
                   + (srow >> 5) * 4 + (srow & 3);

    {
#pragma unroll
        for (int u = 0; u < 4; ++u) {
            const short* gq = Qb + ((size_t)bh * 1024 + qt * 256 + u * 64 + srow) * 64 + schunk * 8;
            __builtin_amdgcn_global_load_lds((const AS1 void*)gq,        (AS3 void*)&smem[16384 + u * 4096 + t * 8],         16, 0, 0);
            __builtin_amdgcn_global_load_lds((const AS1 void*)(gq + 32), (AS3 void*)&smem[16384 + u * 4096 + (t + 256) * 8], 16, 0, 0);
        }
        const short* gk = Kb + ((size_t)bh * 1024 + prow) * 64 + schunk * 8;
        __builtin_amdgcn_global_load_lds((const AS1 void*)gk,        (AS3 void*)&smem[t * 8],         16, 0, 0);
        __builtin_amdgcn_global_load_lds((const AS1 void*)(gk + 32), (AS3 void*)&smem[(t + 256) * 8], 16, 0, 0);
        const short* gv = Vt + ((size_t)bh * 64 + srow) * 1024 + schunk * 8;
        __builtin_amdgcn_global_load_lds((const AS1 void*)gv,        (AS3 void*)&smem[8192 + t * 8],         16, 0, 0);
        __builtin_amdgcn_global_load_lds((const AS1 void*)(gv + 32), (AS3 void*)&smem[8192 + (t + 256) * 8], 16, 0, 0);
    }
    __syncthreads();

    bf16x8 qfrag[4][2];
#pragma unroll
    for (int u = 0; u < 4; ++u)
#pragma unroll
        for (int kh = 0; kh < 2; ++kh)
            qfrag[u][kh] = *(const bf16x8*)&smem[16384 + u * 4096 + ((quad + 4 * kh) * 64 + w * 16 + l16) * 8];

    f32x4 O[4][4];
#pragma unroll
    for (int u = 0; u < 4; ++u)
#pragma unroll
        for (int i = 0; i < 4; ++i) O[u][i] = (f32x4){0.f, 0.f, 0.f, 0.f};
    float l_i[4] = {0.f, 0.f, 0.f, 0.f};

    for (int kt = 0; kt < 16; ++kt) {
        const int cur = kt & 1, nxt = cur ^ 1;
        if (kt < 15) {
            const short* gk = Kb + ((size_t)bh * 1024 + (kt + 1) * 64 + prow) * 64 + schunk * 8;
            __builtin_amdgcn_global_load_lds((const AS1 void*)gk,        (AS3 void*)&smem[nxt * 4096 + t * 8],         16, 0, 0);
            __builtin_amdgcn_global_load_lds((const AS1 void*)(gk + 32), (AS3 void*)&smem[nxt * 4096 + (t + 256) * 8], 16, 0, 0);
            const short* gv = Vt + ((size_t)bh * 64 + srow) * 1024 + (kt + 1) * 64 + schunk * 8;
            __builtin_amdgcn_global_load_lds((const AS1 void*)gv,        (AS3 void*)&smem[8192 + nxt * 4096 + t * 8],         16, 0, 0);
            __builtin_amdgcn_global_load_lds((const AS1 void*)(gv + 32), (AS3 void*)&smem[8192 + nxt * 4096 + (t + 256) * 8], 16, 0, 0);
        }

        const short* Kc = &smem[cur * 4096];
        const short* Vc = &smem[8192 + cur * 4096];

#pragma unroll
        for (int u = 0; u < 4; ++u) {
            f32x4 ST[4];
#pragma unroll
            for (int mi = 0; mi < 4; ++mi) ST[mi] = (f32x4){0.f, 0.f, 0.f, 0.f};
            __builtin_amdgcn_s_setprio(1);
#pragma unroll
            for (int kh = 0; kh < 2; ++kh)
#pragma unroll
                for (int mi = 0; mi < 4; ++mi) {
                    const bf16x8 ka = *(const bf16x8*)&Kc[((quad + 4 * kh) * 64 + mi * 16 + l16) * 8];
                    ST[mi] = __builtin_amdgcn_mfma_f32_16x16x32_bf16(ka, qfrag[u][kh], ST[mi], 0, 0, 0);
                }
            __builtin_amdgcn_s_setprio(0);

            // softmax numerator, fixed reference m=0 (exp2 domain, |s| ~ O(4))
            float p[4][4];
            float rs = 0.f;
#pragma unroll
            for (int mi = 0; mi < 4; ++mi)
#pragma unroll
                for (int rr = 0; rr < 4; ++rr) { p[mi][rr] = EXP2F(ST[mi][rr]); rs += p[mi][rr]; }
            l_i[u] += rs;

            // zero-shuffle pack: lane already holds its PV B-fragment keys.
            union { unsigned uu[4]; bf16x8 v; } pa[2];
#pragma unroll
            for (int kh = 0; kh < 2; ++kh) {
                asm("v_cvt_pk_bf16_f32 %0, %1, %2" : "=v"(pa[kh].uu[0]) : "v"(p[kh][0]),     "v"(p[kh][1]));
                asm("v_cvt_pk_bf16_f32 %0, %1, %2" : "=v"(pa[kh].uu[1]) : "v"(p[kh][2]),     "v"(p[kh][3]));
                asm("v_cvt_pk_bf16_f32 %0, %1, %2" : "=v"(pa[kh].uu[2]) : "v"(p[kh + 2][0]), "v"(p[kh + 2][1]));
                asm("v_cvt_pk_bf16_f32 %0, %1, %2" : "=v"(pa[kh].uu[3]) : "v"(p[kh + 2][2]), "v"(p[kh + 2][3]));
            }

            __builtin_amdgcn_s_setprio(1);
#pragma unroll
            for (int kh = 0; kh < 2; ++kh)
#pragma unroll
                for (int mi = 0; mi < 4; ++mi) {
                    const bf16x8 va = *(const bf16x8*)&Vc[((quad + 4 * kh) * 64 + mi * 16 + l16) * 8];
                    O[u][mi] = __builtin_amdgcn_mfma_f32_16x16x32_bf16(va, pa[kh].v, O[u][mi], 0, 0, 0);
                }
            __builtin_amdgcn_s_setprio(0);
        }

        __syncthreads();
    }

    // complete l_i over the key dim (quad groups)
#pragma unroll
    for (int u = 0; u < 4; ++u) {
        l_i[u] += __shfl_xor(l_i[u], 16);
        l_i[u] += __shfl_xor(l_i[u], 32);
    }

    // Os slab (64 q x 68 f32) overlays the Q region; four passes (u=0..3)
    float* Os = (float*)&smem[16384];
#pragma unroll
    for (int u = 0; u < 4; ++u) {
        __syncthreads();
        const float inv = 1.0f / l_i[u];
#pragma unroll
        for (int mi = 0; mi < 4; ++mi) {
            f32x4 v;
#pragma unroll
            for (int rr = 0; rr < 4; ++rr) v[rr] = O[u][mi][rr] * inv;
            *(f32x4*)&Os[(w * 16 + l16) * 68 + mi * 16 + quad * 4] = v;
        }
        __syncthreads();
        const int q = t >> 2, dbase = (t & 3) * 16;
        float* op = out + ((size_t)bh * 1024 + qt * 256 + u * 64 + q) * 64 + dbase;
#pragma unroll
        for (int i = 0; i < 4; ++i)
            *(float4*)&op[i * 4] = *(float4*)&Os[q * 68 + dbase + i * 4];
    }
}

extern "C" void kernel_launch(void* const* d_in, const int* in_sizes, int n_in,
                              void* d_out, int out_size, void* d_ws, size_t ws_size,
                              hipStream_t stream)
{
    const float* X  = (const float*)d_in[0];
    const float* Wq = (const float*)d_in[1];
    const float* bq = (const float*)d_in[2];
    const float* Wk = (const float*)d_in[3];
    const float* bk = (const float*)d_in[4];
    const float* Wv = (const float*)d_in[5];
    const float* bv = (const float*)d_in[6];
    float* out = (float*)d_out;

    const size_t per = (size_t)8 * HEADS * 1024 * HDIM;   // 8,388,608
    short* Qb = (short*)d_ws;
    short* Kb = Qb + per;
    short* Vt = Kb + per;
    short* Xh = Vt + per;                 // fp16
    short* Wh = Xh + per;                 // fp16 (x256), 3 x 1,048,576

    cast_all<<<4096 + 3 * 512, 256, 0, stream>>>(X, Wq, Wk, Wv, Xh, Wh);

    qkv_mfma<<<dim3(12, 32), 512, 0, stream>>>(Xh, Wh, bq, bk, bv, Qb, Kb, Vt);
    attn_mfma<<<512, 256, 0, stream>>>(Qb, Kb, Vt, out);
}

// Round 13
// 209.779 us; speedup vs baseline: 1.2127x; 1.0001x over previous
//
#include <hip/hip_runtime.h>

#define EMBED 1024
#define HEADS 16
#define HDIM  64

typedef __attribute__((ext_vector_type(8))) short bf16x8;
typedef __attribute__((ext_vector_type(8))) _Float16 f16x8;
typedef __attribute__((ext_vector_type(4))) float f32x4;

#define AS1 __attribute__((address_space(1)))
#define AS3 __attribute__((address_space(3)))

#if __has_builtin(__builtin_amdgcn_exp2f)
#define EXP2F(x) __builtin_amdgcn_exp2f(x)
#else
#define EXP2F(x) exp2f(x)
#endif

__device__ __forceinline__ unsigned bf16_rne(float f) {
    unsigned u = __float_as_uint(f);
    return (u + 0x7FFFu + ((u >> 16) & 1u)) >> 16;
}

// ---------------------------------------------------------------------------
// Kernel 0: fused cast fp32 -> fp16 (RNE) for X (scale 1) and Wq/Wk/Wv
// (scale 256, undone in GEMM epilogue).
// ---------------------------------------------------------------------------
__global__ __launch_bounds__(256)
void cast_all(const float* __restrict__ X,  const float* __restrict__ Wq,
              const float* __restrict__ Wk, const float* __restrict__ Wv,
              short* __restrict__ Xh, short* __restrict__ Wh)
{
    const int bid = blockIdx.x;
    const float* in;
    short* out;
    float scale;
    int base;
    if (bid < 4096) { in = X; out = Xh; scale = 1.0f; base = bid; }
    else {
        const int wsel = (bid - 4096) >> 9;        // 0..2
        in  = (wsel == 0) ? Wq : (wsel == 1) ? Wk : Wv;
        out = Wh + wsel * 1048576;
        scale = 256.0f;
        base = (bid - 4096) & 511;
    }
    const int i = (base * 256 + threadIdx.x) * 8;
    float4 a = *(const float4*)(in + i);
    float4 b = *(const float4*)(in + i + 4);
    float f[8] = {a.x, a.y, a.z, a.w, b.x, b.y, b.z, b.w};
    union { _Float16 h[8]; uint4 v; } H;
#pragma unroll
    for (int e = 0; e < 8; ++e) H.h[e] = (_Float16)(f[e] * scale);
    *(uint4*)(out + i) = H.v;
}

// ---------------------------------------------------------------------------
// Kernel 1: QKV projection -- 256x256 / BK=64 / 8-wave / 8-phase skeleton
// with kh-major A-reuse phases.
// RACE FIX (r12): phase reads occur at TOP of phase p, so they are guarded
// by phase p-1's wait.  Loads reorder only within fence-delimited groups
// (each phase stages one 2-load group; "memory"-clobber vmcnt asm fences).
// vmcnt(2) at p-1 guarantees ALL groups <= p-2 landed -- which is exactly
// the newest data any top-of-phase read touches (A-h1 @p6-prev -> p0-top,
// B-h1 @p7-prev -> p1-top, A1h1 @p2 -> p4-top, B1h1 @p3 -> p5-top).
// The old vmcnt(4) only guaranteed groups <= p-3: those four reads were
// UNCOVERED (timing-dependent -> intermittent replay divergence, r11/r12).
// Prologue drains vmcnt(0) so iter-0 p0/p1 reads are covered.
// ---------------------------------------------------------------------------
#define STAGE_A(buf, h, kt) do {                                              \
    const short* s0_ = baseA + ((h) * 128) * EMBED + (kt) * 64;               \
    short* d_ = &sh[(buf) * 32768 + (h) * 8192 + t * 8];                      \
    __builtin_amdgcn_global_load_lds((const AS1 void*)s0_, (AS3 void*)d_, 16, 0, 0); \
    __builtin_amdgcn_global_load_lds((const AS1 void*)(s0_ + 64 * EMBED), (AS3 void*)(d_ + 4096), 16, 0, 0); \
} while (0)

#define STAGE_B(buf, h, kt) do {                                              \
    const short* s0_ = baseB + ((h) * 32) * EMBED + (kt) * 64;                \
    short* d_ = &sh[(buf) * 32768 + 16384 + (h) * 8192 + t * 8];              \
    __builtin_amdgcn_global_load_lds((const AS1 void*)s0_, (AS3 void*)d_, 16, 0, 0); \
    __builtin_amdgcn_global_load_lds((const AS1 void*)(s0_ + 128 * EMBED), (AS3 void*)(d_ + 4096), 16, 0, 0); \
} while (0)

__global__ __launch_bounds__(512, 2)
void qkv_mfma(const short* __restrict__ Xh, const short* __restrict__ Wh,
              const float* __restrict__ bq, const float* __restrict__ bk,
              const float* __restrict__ bv,
              short* __restrict__ Qb, short* __restrict__ Kb, short* __restrict__ Vt)
{
    __shared__ short sh[65536];   // 128 KiB

    const int t = threadIdx.x;
    const int lane = t & 63, quad = lane >> 4, l16 = lane & 15;
    const int w = t >> 6, wm = w >> 2, wn = w & 3;

    const int n0 = blockIdx.x * 256;   // 0..11 -> Q/K/V column panel
    const int m0 = blockIdx.y * 256;   // 0..31

    const int r  = t >> 3;                       // 0..63
    const int k8 = ((t & 7) ^ (r & 7)) * 8;      // swizzled k element offset
    const short* baseA = Xh + (size_t)(m0 + r) * EMBED + k8;
    const short* baseB = Wh + (size_t)(n0 + (r & 31) + (r >> 5) * 64) * EMBED + k8;

    const int xk0 = ((quad * 16)      ^ ((l16 & 7) << 4)) >> 1;  // ks=0
    const int xk1 = ((64 + quad * 16) ^ ((l16 & 7) << 4)) >> 1;  // ks=1
    const int aOff = wm * 8192 + l16 * 64;                 // + mi*1024
    const int bOff = 16384 + wn * 2048 + l16 * 64;

    f32x4 acc[8][4];
#pragma unroll
    for (int i = 0; i < 8; ++i)
#pragma unroll
        for (int j = 0; j < 4; ++j) acc[i][j] = (f32x4){0.f, 0.f, 0.f, 0.f};

    STAGE_B(0, 0, 0);
    STAGE_A(0, 0, 0);
    STAGE_A(0, 1, 0);
    STAGE_B(0, 1, 0);
    asm volatile("s_waitcnt vmcnt(0)" ::: "memory");   // full drain: iter-0 reads covered
    __builtin_amdgcn_s_barrier();

#pragma unroll 1
    for (int i = 0; i < 8; ++i) {
        const int ktb = 2 * i + 1;
        const int ktc = 2 * i + 2;
        const bool more = (i < 7);
        f16x8 af8[8];
#pragma unroll
        for (int p = 0; p < 8; ++p) {
            const int q = p & 3, buf = p >> 2;
            const int kh  = q >> 1;           // kh0,kh0,kh1,kh1
            const int nih = (q & 1) * 2;      // 0,2,0,2
            const int xk  = kh ? xk1 : xk0;

            // A frags: all 8 mi once per kh (reused across both ni-phases)
            if (nih == 0) {
#pragma unroll
                for (int mi = 0; mi < 8; ++mi)
                    af8[mi] = *(const f16x8*)&sh[buf * 32768 + aOff + mi * 1024 + xk];
            }
            f16x8 bf[2];
#pragma unroll
            for (int ni = 0; ni < 2; ++ni) {
                const int nig = nih + ni;
                bf[ni] = *(const f16x8*)&sh[buf * 32768 + bOff + (nig & 1) * 1024 + (nig >> 1) * 8192 + xk];
            }

            if      (p == 0) STAGE_B(1, 0, ktb);
            else if (p == 1) STAGE_A(1, 0, ktb);
            else if (p == 2) STAGE_A(1, 1, ktb);
            else if (p == 3) STAGE_B(1, 1, ktb);
            else if (more) {
                if      (p == 4) STAGE_B(0, 0, ktc);
                else if (p == 5) STAGE_A(0, 0, ktc);
                else if (p == 6) STAGE_A(0, 1, ktc);
                else             STAGE_B(0, 1, ktc);
            }

            // vmcnt(2): all stage-groups <= (this phase - 1) landed ->
            // next phase's top-of-phase reads are exactly covered.
            if (p < 4 || more) asm volatile("s_waitcnt vmcnt(2)" ::: "memory");
            else if (p == 4)   asm volatile("s_waitcnt vmcnt(0)" ::: "memory");
            else               asm volatile("" ::: "memory");
            __builtin_amdgcn_s_barrier();

            __builtin_amdgcn_s_setprio(1);
#pragma unroll
            for (int mi = 0; mi < 8; ++mi)
#pragma unroll
                for (int ni = 0; ni < 2; ++ni)
                    acc[mi][nih + ni] = __builtin_amdgcn_mfma_f32_16x16x32_f16(
                        af8[mi], bf[ni], acc[mi][nih + ni], 0, 0, 0);
            __builtin_amdgcn_s_setprio(0);
            __builtin_amdgcn_s_barrier();
        }
    }

    // ---- epilogue
    const int mat = n0 >> 10;                 // 0=q 1=k 2=v
    const float* bias = (mat == 0) ? bq : (mat == 1) ? bk : bv;
    const float s = (mat == 0) ? 0.125f * 1.4426950408889634f : 1.0f;
    const float fs = s * (1.0f / 256.0f);
    const int nm0 = n0 & 1023;
    float bias_v[4];
#pragma unroll
    for (int ni = 0; ni < 4; ++ni) bias_v[ni] = bias[nm0 + wn * 64 + ni * 16 + l16] * s;
    const int bidx = m0 >> 10;
    const int l0   = m0 & 1023;

    if (mat == 2) {
        // ---- fused V-transpose epilogue: slab [256 nm][pad 40] x 32 l
#pragma unroll
        for (int mi = 0; mi < 8; ++mi) {
            __syncthreads();
#pragma unroll
            for (int ni = 0; ni < 4; ++ni) {
                const int col = wn * 64 + ni * 16 + l16;
                union { unsigned short us[4]; uint2 v; } pk;
#pragma unroll
                for (int rr = 0; rr < 4; ++rr)
                    pk.us[rr] = (unsigned short)bf16_rne(fmaf(acc[mi][ni][rr], fs, bias_v[ni]));
                *(uint2*)&sh[col * 40 + wm * 16 + quad * 4] = pk.v;   // 4 l-values
            }
            __syncthreads();
            const int nm  = t & 255;             // 0..255 (local col)
            const int wmS = t >> 8;              // 0..1
            uint4 v0 = *(uint4*)&sh[nm * 40 + wmS * 16];
            uint4 v1 = *(uint4*)&sh[nm * 40 + wmS * 16 + 8];
            const int nmg = nm0 + nm;
            const int head = nmg >> 6, d0v = nmg & 63;
            const int l = l0 + wmS * 128 + mi * 16;
            short* pDst = Vt + ((size_t)(bidx * HEADS + head) * 64 + d0v) * 1024 + l;
            *(uint4*)pDst = v0;
            *(uint4*)(pDst + 8) = v1;
        }
        return;
    }

    short* Out = (mat == 0) ? Qb : Kb;
#pragma unroll
    for (int mi = 0; mi < 8; ++mi) {
        __syncthreads();
#pragma unroll
        for (int ni = 0; ni < 4; ++ni) {
            const int col = wn * 64 + ni * 16 + l16;
#pragma unroll
            for (int rr = 0; rr < 4; ++rr) {
                const int srow = wm * 16 + quad * 4 + rr;
                sh[srow * 268 + col] =
                    (short)(unsigned short)bf16_rne(fmaf(acc[mi][ni][rr], fs, bias_v[ni]));
            }
        }
        __syncthreads();
        const int srw = t >> 4;              // 0..31
        const int c0  = (t & 15) * 16;       // 0..240
        uint4 v0 = *(uint4*)&sh[srw * 268 + c0];
        uint4 v1 = *(uint4*)&sh[srw * 268 + c0 + 8];
        const int wmS = srw >> 4, rloc = srw & 15;
        const int l = l0 + wmS * 128 + mi * 16 + rloc;
        const int nm = nm0 + c0;
        const int head = nm >> 6, d0 = nm & 63;
        short* pDst = Out + ((size_t)(bidx * HEADS + head) * 1024 + l) * 64 + d0;
        *(uint4*)pDst = v0;
        *(uint4*)(pDst + 8) = v1;
    }
}

// ---------------------------------------------------------------------------
// Kernel 2: MFMA flash attention, S^T form, ZERO-SHUFFLE P, QBLK=256.
//   Proven structure (prefetch at top, ONE __syncthreads per kt == full
//   vmcnt drain, race-free), four 64-row q sub-tiles per block.
//   LDS 64 KiB: K dbuf | V dbuf | Q (Os overlays Q).  Grid 512 = 2/CU.
//   K staged with rows bit-permuted (prow) so QK^T C-rows land exactly in
//   PV's B-fragment key slots.  Fixed softmax reference m=0 (exp2 domain).
//   XCD swizzle: per XCD 16 bh x 4 qt (qt fastest).
// ---------------------------------------------------------------------------
__global__ __launch_bounds__(256, 2)
void attn_mfma(const short* __restrict__ Qb, const short* __restrict__ Kb,
               const short* __restrict__ Vt, float* __restrict__ out)
{
    __shared__ short smem[32768];   // K 0..8191 | V 8192..16383 | Q 16384..32767

    const int t  = threadIdx.x;
    const int id  = blockIdx.x;                  // 0..511
    const int xcd = id & 7;
    const int loc = id >> 3;                     // 0..63
    const int bh  = xcd * 16 + (loc >> 2);       // 0..127
    const int qt  = loc & 3;                     // 0..3 (256 q rows each)
    const int lane = t & 63, quad = lane >> 4, l16 = lane & 15;
    const int w = t >> 6;
    const int srow = t & 63, schunk = t >> 6;

    // prow = [b4 | b3 b2 | b5 | b1 b0] of srow -> C-layout rows == PV B-slots
    const int prow = ((srow >> 4) & 1) * 32 + ((srow >> 2) & 3) * 8
                   + (srow >> 5) * 4 + (srow & 3);

    {
#pragma unroll
        for (int u = 0; u < 4; ++u) {
            const short* gq = Qb + ((size_t)bh * 1024 + qt * 256 + u * 64 + srow) * 64 + schunk * 8;
            __builtin_amdgcn_global_load_lds((const AS1 void*)gq,        (AS3 void*)&smem[16384 + u * 4096 + t * 8],         16, 0, 0);
            __builtin_amdgcn_global_load_lds((const AS1 void*)(gq + 32), (AS3 void*)&smem[16384 + u * 4096 + (t + 256) * 8], 16, 0, 0);
        }
        const short* gk = Kb + ((size_t)bh * 1024 + prow) * 64 + schunk * 8;
        __builtin_amdgcn_global_load_lds((const AS1 void*)gk,        (AS3 void*)&smem[t * 8],         16, 0, 0);
        __builtin_amdgcn_global_load_lds((const AS1 void*)(gk + 32), (AS3 void*)&smem[(t + 256) * 8], 16, 0, 0);
        const short* gv = Vt + ((size_t)bh * 64 + srow) * 1024 + schunk * 8;
        __builtin_amdgcn_global_load_lds((const AS1 void*)gv,        (AS3 void*)&smem[8192 + t * 8],         16, 0, 0);
        __builtin_amdgcn_global_load_lds((const AS1 void*)(gv + 32), (AS3 void*)&smem[8192 + (t + 256) * 8], 16, 0, 0);
    }
    __syncthreads();

    bf16x8 qfrag[4][2];
#pragma unroll
    for (int u = 0; u < 4; ++u)
#pragma unroll
        for (int kh = 0; kh < 2; ++kh)
            qfrag[u][kh] = *(const bf16x8*)&smem[16384 + u * 4096 + ((quad + 4 * kh) * 64 + w * 16 + l16) * 8];

    f32x4 O[4][4];
#pragma unroll
    for (int u = 0; u < 4; ++u)
#pragma unroll
        for (int i = 0; i < 4; ++i) O[u][i] = (f32x4){0.f, 0.f, 0.f, 0.f};
    float l_i[4] = {0.f, 0.f, 0.f, 0.f};

    for (int kt = 0; kt < 16; ++kt) {
        const int cur = kt & 1, nxt = cur ^ 1;
        if (kt < 15) {
            const short* gk = Kb + ((size_t)bh * 1024 + (kt + 1) * 64 + prow) * 64 + schunk * 8;
            __builtin_amdgcn_global_load_lds((const AS1 void*)gk,        (AS3 void*)&smem[nxt * 4096 + t * 8],         16, 0, 0);
            __builtin_amdgcn_global_load_lds((const AS1 void*)(gk + 32), (AS3 void*)&smem[nxt * 4096 + (t + 256) * 8], 16, 0, 0);
            const short* gv = Vt + ((size_t)bh * 64 + srow) * 1024 + (kt + 1) * 64 + schunk * 8;
            __builtin_amdgcn_global_load_lds((const AS1 void*)gv,        (AS3 void*)&smem[8192 + nxt * 4096 + t * 8],         16, 0, 0);
            __builtin_amdgcn_global_load_lds((const AS1 void*)(gv + 32), (AS3 void*)&smem[8192 + nxt * 4096 + (t + 256) * 8], 16, 0, 0);
        }

        const short* Kc = &smem[cur * 4096];
        const short* Vc = &smem[8192 + cur * 4096];

#pragma unroll
        for (int u = 0; u < 4; ++u) {
            f32x4 ST[4];
#pragma unroll
            for (int mi = 0; mi < 4; ++mi) ST[mi] = (f32x4){0.f, 0.f, 0.f, 0.f};
            __builtin_amdgcn_s_setprio(1);
#pragma unroll
            for (int kh = 0; kh < 2; ++kh)
#pragma unroll
                for (int mi = 0; mi < 4; ++mi) {
                    const bf16x8 ka = *(const bf16x8*)&Kc[((quad + 4 * kh) * 64 + mi * 16 + l16) * 8];
                    ST[mi] = __builtin_amdgcn_mfma_f32_16x16x32_bf16(ka, qfrag[u][kh], ST[mi], 0, 0, 0);
                }
            __builtin_amdgcn_s_setprio(0);

            // softmax numerator, fixed reference m=0 (exp2 domain, |s| ~ O(4))
            float p[4][4];
            float rs = 0.f;
#pragma unroll
            for (int mi = 0; mi < 4; ++mi)
#pragma unroll
                for (int rr = 0; rr < 4; ++rr) { p[mi][rr] = EXP2F(ST[mi][rr]); rs += p[mi][rr]; }
            l_i[u] += rs;

            // zero-shuffle pack: lane already holds its PV B-fragment keys.
            union { unsigned uu[4]; bf16x8 v; } pa[2];
#pragma unroll
            for (int kh = 0; kh < 2; ++kh) {
                asm("v_cvt_pk_bf16_f32 %0, %1, %2" : "=v"(pa[kh].uu[0]) : "v"(p[kh][0]),     "v"(p[kh][1]));
                asm("v_cvt_pk_bf16_f32 %0, %1, %2" : "=v"(pa[kh].uu[1]) : "v"(p[kh][2]),     "v"(p[kh][3]));
                asm("v_cvt_pk_bf16_f32 %0, %1, %2" : "=v"(pa[kh].uu[2]) : "v"(p[kh + 2][0]), "v"(p[kh + 2][1]));
                asm("v_cvt_pk_bf16_f32 %0, %1, %2" : "=v"(pa[kh].uu[3]) : "v"(p[kh + 2][2]), "v"(p[kh + 2][3]));
            }

            __builtin_amdgcn_s_setprio(1);
#pragma unroll
            for (int kh = 0; kh < 2; ++kh)
#pragma unroll
                for (int mi = 0; mi < 4; ++mi) {
                    const bf16x8 va = *(const bf16x8*)&Vc[((quad + 4 * kh) * 64 + mi * 16 + l16) * 8];
                    O[u][mi] = __builtin_amdgcn_mfma_f32_16x16x32_bf16(va, pa[kh].v, O[u][mi], 0, 0, 0);
                }
            __builtin_amdgcn_s_setprio(0);
        }

        __syncthreads();
    }

    // complete l_i over the key dim (quad groups)
#pragma unroll
    for (int u = 0; u < 4; ++u) {
        l_i[u] += __shfl_xor(l_i[u], 16);
        l_i[u] += __shfl_xor(l_i[u], 32);
    }

    // Os slab (64 q x 68 f32) overlays the Q region; four passes (u=0..3)
    float* Os = (float*)&smem[16384];
#pragma unroll
    for (int u = 0; u < 4; ++u) {
        __syncthreads();
        const float inv = 1.0f / l_i[u];
#pragma unroll
        for (int mi = 0; mi < 4; ++mi) {
            f32x4 v;
#pragma unroll
            for (int rr = 0; rr < 4; ++rr) v[rr] = O[u][mi][rr] * inv;
            *(f32x4*)&Os[(w * 16 + l16) * 68 + mi * 16 + quad * 4] = v;
        }
        __syncthreads();
        const int q = t >> 2, dbase = (t & 3) * 16;
        float* op = out + ((size_t)bh * 1024 + qt * 256 + u * 64 + q) * 64 + dbase;
#pragma unroll
        for (int i = 0; i < 4; ++i)
            *(float4*)&op[i * 4] = *(float4*)&Os[q * 68 + dbase + i * 4];
    }
}

extern "C" void kernel_launch(void* const* d_in, const int* in_sizes, int n_in,
                              void* d_out, int out_size, void* d_ws, size_t ws_size,
                              hipStream_t stream)
{
    const float* X  = (const float*)d_in[0];
    const float* Wq = (const float*)d_in[1];
    const float* bq = (const float*)d_in[2];
    const float* Wk = (const float*)d_in[3];
    const float* bk = (const float*)d_in[4];
    const float* Wv = (const float*)d_in[5];
    const float* bv = (const float*)d_in[6];
    float* out = (float*)d_out;

    const size_t per = (size_t)8 * HEADS * 1024 * HDIM;   // 8,388,608
    short* Qb = (short*)d_ws;
    short* Kb = Qb + per;
    short* Vt = Kb + per;
    short* Xh = Vt + per;                 // fp16
    short* Wh = Xh + per;                 // fp16 (x256), 3 x 1,048,576

    cast_all<<<4096 + 3 * 512, 256, 0, stream>>>(X, Wq, Wk, Wv, Xh, Wh);

    qkv_mfma<<<dim3(12, 32), 512, 0, stream>>>(Xh, Wh, bq, bk, bv, Qb, Kb, Vt);
    attn_mfma<<<512, 256, 0, stream>>>(Qb, Kb, Vt, out);
}